// Round 8
// baseline (60.008 us; speedup 1.0000x reference)
//
#include <hip/hip_runtime.h>
#include <hip/hip_bf16.h>
#include <math.h>

#define T_DIM 32
#define B_DIM 128
#define D_DIM 512
#define M_DIM 1024
#define R_DIM (T_DIM * B_DIM)          // 4096 proj rows

constexpr float DT = 0.1875f;          // 3.0 / 16
constexpr float INV_2PI = 0.15915494309189535f;

typedef __attribute__((ext_vector_type(8))) short bf16x8;   // 8 bf16 = 4 VGPR
typedef __attribute__((ext_vector_type(4))) float f32x4;    // MFMA acc

__device__ __forceinline__ ushort f2bf(float f) {           // RNE fp32->bf16
    unsigned u = __float_as_uint(f);
    u += 0x7FFFu + ((u >> 16) & 1u);
    return (ushort)(u >> 16);
}
__device__ __forceinline__ float bf_lo(unsigned u) { return __uint_as_float(u << 16); }
__device__ __forceinline__ float bf_hi(unsigned u) { return __uint_as_float(u & 0xFFFF0000u); }

// ---------- K1: prep. blocks 0..63: A colnorm + transpose -> ant (bf16, [m][d]).
//                blocks 64..319: z fp32 -> bf16 copy. ----------
__global__ __launch_bounds__(256) void prep_kernel(const float* __restrict__ A,
                                                   const float* __restrict__ z,
                                                   ushort* __restrict__ zb,
                                                   ushort* __restrict__ ant) {
    const int bid = blockIdx.x;
    const int tid = threadIdx.x;

    if (bid >= 64) {                       // ---- zconv: 256 blocks x 8192 floats ----
        const size_t base = (size_t)(bid - 64) * 8192 + tid * 8;
#pragma unroll
        for (int j = 0; j < 4; ++j) {
            const size_t i = base + j * 2048;
            const float4 a = *reinterpret_cast<const float4*>(&z[i]);
            const float4 b = *reinterpret_cast<const float4*>(&z[i + 4]);
            uint4 p;
            p.x = (unsigned)f2bf(a.x) | ((unsigned)f2bf(a.y) << 16);
            p.y = (unsigned)f2bf(a.z) | ((unsigned)f2bf(a.w) << 16);
            p.z = (unsigned)f2bf(b.x) | ((unsigned)f2bf(b.y) << 16);
            p.w = (unsigned)f2bf(b.z) | ((unsigned)f2bf(b.w) << 16);
            *reinterpret_cast<uint4*>(&zb[i]) = p;
        }
        return;
    }

    // ---- norm + transpose for 16 m-columns ----
    __shared__ float red[256];
    __shared__ float inv[16];
    __shared__ float tile[128][17];

    const int mB = bid * 16;
    const int mo = tid & 15;
    const int dg = tid >> 4;               // 16 groups of 32 d
    float ss = 0.0f;
#pragma unroll 4
    for (int i = 0; i < 32; ++i) {
        const float v = A[(size_t)(dg * 32 + i) * M_DIM + mB + mo];
        ss = fmaf(v, v, ss);
    }
    red[tid] = ss;
    __syncthreads();
    for (int s = 128; s >= 16; s >>= 1) {
        if (tid < s) red[tid] += red[tid + s];
        __syncthreads();
    }
    if (tid < 16) inv[tid] = 1.0f / fmaxf(sqrtf(red[tid]), 1e-12f);

#pragma unroll
    for (int ch = 0; ch < 4; ++ch) {       // 4 chunks of 128 d
        const int dB = ch * 128;
#pragma unroll
        for (int q = 0; q < 2; ++q) {
            const int s  = tid + 256 * q;  // 0..511
            const int r  = s >> 2;         // 0..127
            const int c4 = (s & 3) * 4;    // 0,4,8,12
            const float4 v = *reinterpret_cast<const float4*>(
                &A[(size_t)(dB + r) * M_DIM + mB + c4]);
            tile[r][c4]     = v.x;
            tile[r][c4 + 1] = v.y;
            tile[r][c4 + 2] = v.z;
            tile[r][c4 + 3] = v.w;
        }
        __syncthreads();
        {
            const int m  = tid >> 4;       // 0..15
            const int d8 = (tid & 15) * 8; // 0..120
            const float sc = inv[m];
            uint4 p;
            p.x = (unsigned)f2bf(tile[d8 + 0][m] * sc) | ((unsigned)f2bf(tile[d8 + 1][m] * sc) << 16);
            p.y = (unsigned)f2bf(tile[d8 + 2][m] * sc) | ((unsigned)f2bf(tile[d8 + 3][m] * sc) << 16);
            p.z = (unsigned)f2bf(tile[d8 + 4][m] * sc) | ((unsigned)f2bf(tile[d8 + 5][m] * sc) << 16);
            p.w = (unsigned)f2bf(tile[d8 + 6][m] * sc) | ((unsigned)f2bf(tile[d8 + 7][m] * sc) << 16);
            *reinterpret_cast<uint4*>(&ant[(size_t)(mB + m) * D_DIM + dB + d8]) = p;
        }
        __syncthreads();
    }
}

// ---------- K2: bf16 MFMA GEMM -> proj_cm (COLUMN-major [M][R], bf16) ----------
// 128x128 tile, 4 waves 2x2, 4x4 frags of 16x16x32, BK=32, reg-staged LDS.
// (Validated in R6: absmax 0.)
__global__ __launch_bounds__(256) void gemm_kernel(const ushort* __restrict__ zb,
                                                   const ushort* __restrict__ ant,
                                                   ushort* __restrict__ proj_cm) {
    __shared__ __align__(16) ushort As[128][32];
    __shared__ __align__(16) ushort Bs[128][32];

    const int tid    = threadIdx.x;
    const int colBlk = blockIdx.x * 128;   // 8
    const int rowBlk = blockIdx.y * 128;   // 32 (= t)
    const int wave = tid >> 6;
    const int lane = tid & 63;
    const int wr   = wave >> 1;
    const int wc   = wave & 1;
    const int l15  = lane & 15;
    const int lhi  = lane >> 4;

    const int sr = tid >> 2;
    const int sq = tid & 3;

    f32x4 acc[4][4];
#pragma unroll
    for (int fm = 0; fm < 4; ++fm)
#pragma unroll
        for (int fn = 0; fn < 4; ++fn) acc[fm][fn] = (f32x4)(0.0f);

    uint4 aR[2], bR[2];
#pragma unroll
    for (int c = 0; c < 2; ++c) {
        const int r = sr + c * 64;
        aR[c] = *reinterpret_cast<const uint4*>(&zb[(size_t)(rowBlk + r) * D_DIM + sq * 8]);
        bR[c] = *reinterpret_cast<const uint4*>(&ant[(size_t)(colBlk + r) * D_DIM + sq * 8]);
    }

    for (int it = 0; it < 16; ++it) {
        __syncthreads();
#pragma unroll
        for (int c = 0; c < 2; ++c) {
            *reinterpret_cast<uint4*>(&As[sr + c * 64][sq * 8]) = aR[c];
            *reinterpret_cast<uint4*>(&Bs[sr + c * 64][sq * 8]) = bR[c];
        }
        __syncthreads();

        if (it < 15) {
            const int k0 = (it + 1) * 32;
#pragma unroll
            for (int c = 0; c < 2; ++c) {
                const int r = sr + c * 64;
                aR[c] = *reinterpret_cast<const uint4*>(&zb[(size_t)(rowBlk + r) * D_DIM + k0 + sq * 8]);
                bR[c] = *reinterpret_cast<const uint4*>(&ant[(size_t)(colBlk + r) * D_DIM + k0 + sq * 8]);
            }
        }

        bf16x8 af[4], bfr[4];
#pragma unroll
        for (int fm = 0; fm < 4; ++fm)
            af[fm] = *reinterpret_cast<const bf16x8*>(&As[wr * 64 + fm * 16 + l15][lhi * 8]);
#pragma unroll
        for (int fn = 0; fn < 4; ++fn)
            bfr[fn] = *reinterpret_cast<const bf16x8*>(&Bs[wc * 64 + fn * 16 + l15][lhi * 8]);
#pragma unroll
        for (int fm = 0; fm < 4; ++fm)
#pragma unroll
            for (int fn = 0; fn < 4; ++fn)
                acc[fm][fn] = __builtin_amdgcn_mfma_f32_16x16x32_bf16(af[fm], bfr[fn], acc[fm][fn], 0, 0, 0);
    }

    // epilogue: col=l15 -> B row (m), row=lhi*4+reg -> A row (b). 4 regs = 4 consec rows.
#pragma unroll
    for (int fn = 0; fn < 4; ++fn) {
        const int m = colBlk + wc * 64 + fn * 16 + l15;
#pragma unroll
        for (int fm = 0; fm < 4; ++fm) {
            const int r0 = rowBlk + wr * 64 + fm * 16 + lhi * 4;
            ushort4 o;
            o.x = f2bf(acc[fm][fn][0]);
            o.y = f2bf(acc[fm][fn][1]);
            o.z = f2bf(acc[fm][fn][2]);
            o.w = f2bf(acc[fm][fn][3]);
            *reinterpret_cast<ushort4*>(&proj_cm[(size_t)m * R_DIM + r0]) = o;
        }
    }
}

// ---------- K3: CF statistic, k-on-threads (2 accumulators/thread, spill-proof) ----------
// grid (64 mchunks, 32 t), 256 thr: thread = (m local 0..15, knot k 1..16).
__global__ __launch_bounds__(256) void stat_kernel(const ushort* __restrict__ proj_cm,
                                                   float* __restrict__ partials) {
    __shared__ float tile[128][17];     // [b][m], padded
    __shared__ float sred[4];

    const int tid = threadIdx.x;
    const int mB  = blockIdx.x * 16;    // 64 chunks
    const int t   = blockIdx.y;         // 32

    // ---- stage proj tile: 16 m x 128 b, bf16 -> f32 ----
    {
        const int m  = tid >> 4;        // 0..15
        const int bq = tid & 15;        // 0..15, 8 b's each
        const uint4 v = *reinterpret_cast<const uint4*>(
            &proj_cm[(size_t)(mB + m) * R_DIM + t * B_DIM + bq * 8]);
        const int b0 = bq * 8;
        tile[b0 + 0][m] = bf_lo(v.x);  tile[b0 + 1][m] = bf_hi(v.x);
        tile[b0 + 2][m] = bf_lo(v.y);  tile[b0 + 3][m] = bf_hi(v.y);
        tile[b0 + 4][m] = bf_lo(v.z);  tile[b0 + 5][m] = bf_hi(v.z);
        tile[b0 + 6][m] = bf_lo(v.w);  tile[b0 + 7][m] = bf_hi(v.w);
    }
    __syncthreads();

    const int m  = tid & 15;
    const int kk = (tid >> 4) + 1;      // knot 1..16 (knot 0 contributes exactly 0)
    const float kf = (float)kk * (DT * INV_2PI);   // revolutions per unit proj

    float ca = 0.0f, sa = 0.0f;
#pragma unroll 8
    for (int b = 0; b < 128; ++b) {
        const float a = tile[b][m] * kf;
        const float r = a - floorf(a);             // v_fract
        sa += __builtin_amdgcn_sinf(r);
        ca += __builtin_amdgcn_cosf(r);
    }

    const float tk = (float)kk * DT;
    const float g  = __expf(-0.5f * tk * tk);
    const float w  = ((kk == 16) ? DT : 2.0f * DT) * g;
    const float invB = 1.0f / 128.0f;
    const float cm = fmaf(ca, invB, -g);
    const float sm = sa * invB;
    float e = w * fmaf(cm, cm, sm * sm);

    // block scalar reduce (wave butterfly + LDS)
#pragma unroll
    for (int msk = 1; msk < 64; msk <<= 1) e += __shfl_xor(e, msk);
    if ((tid & 63) == 0) sred[tid >> 6] = e;
    __syncthreads();
    if (tid == 0)
        partials[blockIdx.y * 64 + blockIdx.x] = sred[0] + sred[1] + sred[2] + sred[3];
}

// ---------- K4: final reduce of 2048 partials ----------
__global__ __launch_bounds__(256) void finalize_kernel(const float* __restrict__ partials,
                                                       float* __restrict__ out) {
    __shared__ float red[256];
    const int tid = threadIdx.x;
    float s = 0.0f;
#pragma unroll
    for (int j = 0; j < 8; ++j) s += partials[tid + 256 * j];
    red[tid] = s;
    __syncthreads();
    for (int st = 128; st > 0; st >>= 1) {
        if (tid < st) red[tid] += red[tid + st];
        __syncthreads();
    }
    // out = (1/(T*M)) * B * sum = sum / 256
    if (tid == 0) out[0] = red[0] * (1.0f / 256.0f);
}

extern "C" void kernel_launch(void* const* d_in, const int* in_sizes, int n_in,
                              void* d_out, int out_size, void* d_ws, size_t ws_size,
                              hipStream_t stream) {
    const float* z = (const float*)d_in[0];   // (32,128,512)
    const float* A = (const float*)d_in[1];   // (512,1024)
    float* out = (float*)d_out;

    char* ws = (char*)d_ws;
    ushort* zb       = (ushort*)ws;                               // 4 MB
    ushort* ant      = (ushort*)(ws + 4 * 1024 * 1024);           // 1 MB
    ushort* proj_cm  = (ushort*)(ws + 5 * 1024 * 1024);           // 8 MB
    float*  partials = (float*)(ws + 13 * 1024 * 1024);           // 8 KB

    prep_kernel<<<320, 256, 0, stream>>>(A, z, zb, ant);
    gemm_kernel<<<dim3(M_DIM / 128, R_DIM / 128), 256, 0, stream>>>(zb, ant, proj_cm);
    stat_kernel<<<dim3(64, T_DIM), 256, 0, stream>>>(proj_cm, partials);
    finalize_kernel<<<1, 256, 0, stream>>>(partials, out);
}

// Round 9
// 47.900 us; speedup vs baseline: 1.2528x; 1.2528x over previous
//
#include <hip/hip_runtime.h>
#include <hip/hip_bf16.h>
#include <math.h>

#define T_DIM 32
#define B_DIM 128
#define D_DIM 512
#define M_DIM 1024
#define R_DIM (T_DIM * B_DIM)          // 4096 proj rows

constexpr float DT = 0.1875f;          // 3.0 / 16
constexpr float INV_2PI = 0.15915494309189535f;

typedef __attribute__((ext_vector_type(8))) short bf16x8;   // 8 bf16 = 4 VGPR
typedef __attribute__((ext_vector_type(4))) float f32x4;    // MFMA acc

__device__ __forceinline__ ushort f2bf(float f) {           // RNE fp32->bf16
    unsigned u = __float_as_uint(f);
    u += 0x7FFFu + ((u >> 16) & 1u);
    return (ushort)(u >> 16);
}
__device__ __forceinline__ float bf_lo(unsigned u) { return __uint_as_float(u << 16); }
__device__ __forceinline__ float bf_hi(unsigned u) { return __uint_as_float(u & 0xFFFF0000u); }

// async global->LDS, 16B per lane; LDS dest is wave-uniform base + lane*16.
__device__ __forceinline__ void gload16(const void* g, void* l) {
    __builtin_amdgcn_global_load_lds(
        (const __attribute__((address_space(1))) void*)g,
        (__attribute__((address_space(3))) void*)l, 16, 0, 0);
}

// ---------- K1: prep. blocks 0..63: A colnorm + transpose -> ant (bf16, [m][d]).
//                blocks 64..319: z fp32 -> bf16 copy. (validated R8) ----------
__global__ __launch_bounds__(256) void prep_kernel(const float* __restrict__ A,
                                                   const float* __restrict__ z,
                                                   ushort* __restrict__ zb,
                                                   ushort* __restrict__ ant) {
    const int bid = blockIdx.x;
    const int tid = threadIdx.x;

    if (bid >= 64) {                       // ---- zconv: 256 blocks x 8192 floats ----
        const size_t base = (size_t)(bid - 64) * 8192 + tid * 8;
#pragma unroll
        for (int j = 0; j < 4; ++j) {
            const size_t i = base + j * 2048;
            const float4 a = *reinterpret_cast<const float4*>(&z[i]);
            const float4 b = *reinterpret_cast<const float4*>(&z[i + 4]);
            uint4 p;
            p.x = (unsigned)f2bf(a.x) | ((unsigned)f2bf(a.y) << 16);
            p.y = (unsigned)f2bf(a.z) | ((unsigned)f2bf(a.w) << 16);
            p.z = (unsigned)f2bf(b.x) | ((unsigned)f2bf(b.y) << 16);
            p.w = (unsigned)f2bf(b.z) | ((unsigned)f2bf(b.w) << 16);
            *reinterpret_cast<uint4*>(&zb[i]) = p;
        }
        return;
    }

    __shared__ float red[256];
    __shared__ float inv[16];
    __shared__ float tile[128][17];

    const int mB = bid * 16;
    const int mo = tid & 15;
    const int dg = tid >> 4;
    float ss = 0.0f;
#pragma unroll 4
    for (int i = 0; i < 32; ++i) {
        const float v = A[(size_t)(dg * 32 + i) * M_DIM + mB + mo];
        ss = fmaf(v, v, ss);
    }
    red[tid] = ss;
    __syncthreads();
    for (int s = 128; s >= 16; s >>= 1) {
        if (tid < s) red[tid] += red[tid + s];
        __syncthreads();
    }
    if (tid < 16) inv[tid] = 1.0f / fmaxf(sqrtf(red[tid]), 1e-12f);

#pragma unroll
    for (int ch = 0; ch < 4; ++ch) {
        const int dB = ch * 128;
#pragma unroll
        for (int q = 0; q < 2; ++q) {
            const int s  = tid + 256 * q;
            const int r  = s >> 2;
            const int c4 = (s & 3) * 4;
            const float4 v = *reinterpret_cast<const float4*>(
                &A[(size_t)(dB + r) * M_DIM + mB + c4]);
            tile[r][c4]     = v.x;
            tile[r][c4 + 1] = v.y;
            tile[r][c4 + 2] = v.z;
            tile[r][c4 + 3] = v.w;
        }
        __syncthreads();
        {
            const int m  = tid >> 4;
            const int d8 = (tid & 15) * 8;
            const float sc = inv[m];
            uint4 p;
            p.x = (unsigned)f2bf(tile[d8 + 0][m] * sc) | ((unsigned)f2bf(tile[d8 + 1][m] * sc) << 16);
            p.y = (unsigned)f2bf(tile[d8 + 2][m] * sc) | ((unsigned)f2bf(tile[d8 + 3][m] * sc) << 16);
            p.z = (unsigned)f2bf(tile[d8 + 4][m] * sc) | ((unsigned)f2bf(tile[d8 + 5][m] * sc) << 16);
            p.w = (unsigned)f2bf(tile[d8 + 6][m] * sc) | ((unsigned)f2bf(tile[d8 + 7][m] * sc) << 16);
            *reinterpret_cast<uint4*>(&ant[(size_t)(mB + m) * D_DIM + dB + d8]) = p;
        }
        __syncthreads();
    }
}

// ---------- K2: bf16 MFMA GEMM via global_load_lds -> proj_cm ([M][R] bf16) ----------
// m97 structure: 128x128 tile, BK=64, linear LDS, 2-barrier loop, 4 waves 2x2.
__global__ __launch_bounds__(256) void gemm_kernel(const ushort* __restrict__ zb,
                                                   const ushort* __restrict__ ant,
                                                   ushort* __restrict__ proj_cm) {
    __shared__ __align__(16) ushort As[128 * 64];   // [row][64] linear (gload_lds needs it)
    __shared__ __align__(16) ushort Bs[128 * 64];

    const int tid    = threadIdx.x;
    const int colBlk = blockIdx.x * 128;   // 8  (m)
    const int rowBlk = blockIdx.y * 128;   // 32 (b-rows = one t)
    const int wave = tid >> 6;
    const int lane = tid & 63;
    const int wr   = wave >> 1;
    const int wc   = wave & 1;
    const int l15  = lane & 15;
    const int lhi  = lane >> 4;

    const int l8 = lane >> 3;              // 0..7  (row within 8-row group)
    const int c8 = (lane & 7) * 8;         // elem col within BK

    f32x4 acc[4][4];
#pragma unroll
    for (int fm = 0; fm < 4; ++fm)
#pragma unroll
        for (int fn = 0; fn < 4; ++fn) acc[fm][fn] = (f32x4)(0.0f);

#pragma unroll
    for (int it = 0; it < 8; ++it) {
        const int k0 = it * 64;
        // stage: each wave loads 4x8 rows of A and of B (1KB per gload16)
#pragma unroll
        for (int j = 0; j < 4; ++j) {
            const int r = wave * 32 + j * 8;
            gload16(&zb[(size_t)(rowBlk + r + l8) * D_DIM + k0 + c8], &As[r * 64]);
            gload16(&ant[(size_t)(colBlk + r + l8) * D_DIM + k0 + c8], &Bs[r * 64]);
        }
        __syncthreads();                   // drains vmcnt -> LDS data visible

#pragma unroll
        for (int ks = 0; ks < 2; ++ks) {
            bf16x8 af[4], bfr[4];
#pragma unroll
            for (int fm = 0; fm < 4; ++fm)
                af[fm] = *reinterpret_cast<const bf16x8*>(&As[(wr * 64 + fm * 16 + l15) * 64 + ks * 32 + lhi * 8]);
#pragma unroll
            for (int fn = 0; fn < 4; ++fn)
                bfr[fn] = *reinterpret_cast<const bf16x8*>(&Bs[(wc * 64 + fn * 16 + l15) * 64 + ks * 32 + lhi * 8]);
#pragma unroll
            for (int fm = 0; fm < 4; ++fm)
#pragma unroll
                for (int fn = 0; fn < 4; ++fn)
                    acc[fm][fn] = __builtin_amdgcn_mfma_f32_16x16x32_bf16(af[fm], bfr[fn], acc[fm][fn], 0, 0, 0);
        }
        __syncthreads();                   // readers done before next-iter overwrite
    }

    // epilogue (validated R6): col=l15 -> m, row=lhi*4+reg -> b-row; 4 regs consecutive.
#pragma unroll
    for (int fn = 0; fn < 4; ++fn) {
        const int m = colBlk + wc * 64 + fn * 16 + l15;
#pragma unroll
        for (int fm = 0; fm < 4; ++fm) {
            const int r0 = rowBlk + wr * 64 + fm * 16 + lhi * 4;
            ushort4 o;
            o.x = f2bf(acc[fm][fn][0]);
            o.y = f2bf(acc[fm][fn][1]);
            o.z = f2bf(acc[fm][fn][2]);
            o.w = f2bf(acc[fm][fn][3]);
            *reinterpret_cast<ushort4*>(&proj_cm[(size_t)m * R_DIM + r0]) = o;
        }
    }
}

// ---------- K3: CF statistic, k-on-threads, [m][b] LDS + ds_read_b128 ----------
// grid (64 mchunks, 32 t), 256 thr: thread = (m 0..15, knot 1..16). (math validated R8)
__global__ __launch_bounds__(256) void stat_kernel(const ushort* __restrict__ proj_cm,
                                                   float* __restrict__ partials) {
    __shared__ float tile[16][132];     // [m][b], row stride 132 (2-way max on reads)
    __shared__ float sred[4];

    const int tid = threadIdx.x;
    const int mB  = blockIdx.x * 16;    // 64 chunks
    const int t   = blockIdx.y;         // 32

    {   // stage: 16 m x 128 b, bf16 -> f32
        const int m  = tid >> 4;        // 0..15
        const int bq = tid & 15;        // 8 b's each
        const uint4 v = *reinterpret_cast<const uint4*>(
            &proj_cm[(size_t)(mB + m) * R_DIM + t * B_DIM + bq * 8]);
        const int b0 = bq * 8;
        tile[m][b0 + 0] = bf_lo(v.x);  tile[m][b0 + 1] = bf_hi(v.x);
        tile[m][b0 + 2] = bf_lo(v.y);  tile[m][b0 + 3] = bf_hi(v.y);
        tile[m][b0 + 4] = bf_lo(v.z);  tile[m][b0 + 5] = bf_hi(v.z);
        tile[m][b0 + 6] = bf_lo(v.w);  tile[m][b0 + 7] = bf_hi(v.w);
    }
    __syncthreads();

    const int m  = tid & 15;
    const int kk = (tid >> 4) + 1;      // knot 1..16 (knot 0 contributes exactly 0)
    const float kf = (float)kk * (DT * INV_2PI);

    float ca = 0.0f, sa = 0.0f;
#pragma unroll 4
    for (int b = 0; b < 128; b += 4) {
        const float4 v = *reinterpret_cast<const float4*>(&tile[m][b]);  // ds_read_b128
        {
            const float a0 = v.x * kf; const float r0 = a0 - floorf(a0);
            sa += __builtin_amdgcn_sinf(r0); ca += __builtin_amdgcn_cosf(r0);
            const float a1 = v.y * kf; const float r1 = a1 - floorf(a1);
            sa += __builtin_amdgcn_sinf(r1); ca += __builtin_amdgcn_cosf(r1);
            const float a2 = v.z * kf; const float r2 = a2 - floorf(a2);
            sa += __builtin_amdgcn_sinf(r2); ca += __builtin_amdgcn_cosf(r2);
            const float a3 = v.w * kf; const float r3 = a3 - floorf(a3);
            sa += __builtin_amdgcn_sinf(r3); ca += __builtin_amdgcn_cosf(r3);
        }
    }

    const float tk = (float)kk * DT;
    const float g  = __expf(-0.5f * tk * tk);
    const float w  = ((kk == 16) ? DT : 2.0f * DT) * g;
    const float invB = 1.0f / 128.0f;
    const float cm = fmaf(ca, invB, -g);
    const float sm = sa * invB;
    float e = w * fmaf(cm, cm, sm * sm);

#pragma unroll
    for (int msk = 1; msk < 64; msk <<= 1) e += __shfl_xor(e, msk);
    if ((tid & 63) == 0) sred[tid >> 6] = e;
    __syncthreads();
    if (tid == 0)
        partials[blockIdx.y * 64 + blockIdx.x] = sred[0] + sred[1] + sred[2] + sred[3];
}

// ---------- K4: final reduce of 2048 partials ----------
__global__ __launch_bounds__(256) void finalize_kernel(const float* __restrict__ partials,
                                                       float* __restrict__ out) {
    __shared__ float red[256];
    const int tid = threadIdx.x;
    float s = 0.0f;
#pragma unroll
    for (int j = 0; j < 8; ++j) s += partials[tid + 256 * j];
    red[tid] = s;
    __syncthreads();
    for (int st = 128; st > 0; st >>= 1) {
        if (tid < st) red[tid] += red[tid + st];
        __syncthreads();
    }
    if (tid == 0) out[0] = red[0] * (1.0f / 256.0f);   // (1/(T*M)) * B
}

extern "C" void kernel_launch(void* const* d_in, const int* in_sizes, int n_in,
                              void* d_out, int out_size, void* d_ws, size_t ws_size,
                              hipStream_t stream) {
    const float* z = (const float*)d_in[0];   // (32,128,512)
    const float* A = (const float*)d_in[1];   // (512,1024)
    float* out = (float*)d_out;

    char* ws = (char*)d_ws;
    ushort* zb       = (ushort*)ws;                               // 4 MB
    ushort* ant      = (ushort*)(ws + 4 * 1024 * 1024);           // 1 MB
    ushort* proj_cm  = (ushort*)(ws + 5 * 1024 * 1024);           // 8 MB
    float*  partials = (float*)(ws + 13 * 1024 * 1024);           // 8 KB

    prep_kernel<<<320, 256, 0, stream>>>(A, z, zb, ant);
    gemm_kernel<<<dim3(M_DIM / 128, R_DIM / 128), 256, 0, stream>>>(zb, ant, proj_cm);
    stat_kernel<<<dim3(64, T_DIM), 256, 0, stream>>>(proj_cm, partials);
    finalize_kernel<<<1, 256, 0, stream>>>(partials, out);
}

// Round 10
// 47.075 us; speedup vs baseline: 1.2747x; 1.0175x over previous
//
#include <hip/hip_runtime.h>
#include <hip/hip_bf16.h>
#include <math.h>

#define T_DIM 32
#define B_DIM 128
#define D_DIM 512
#define M_DIM 1024
#define R_DIM (T_DIM * B_DIM)          // 4096 proj rows

constexpr float DT = 0.1875f;          // 3.0 / 16
constexpr float INV_2PI = 0.15915494309189535f;

typedef __attribute__((ext_vector_type(8))) short bf16x8;   // 8 bf16 = 4 VGPR
typedef __attribute__((ext_vector_type(4))) float f32x4;    // MFMA acc

__device__ __forceinline__ ushort f2bf(float f) {           // RNE fp32->bf16
    unsigned u = __float_as_uint(f);
    u += 0x7FFFu + ((u >> 16) & 1u);
    return (ushort)(u >> 16);
}
__device__ __forceinline__ float bf_lo(unsigned u) { return __uint_as_float(u << 16); }
__device__ __forceinline__ float bf_hi(unsigned u) { return __uint_as_float(u & 0xFFFF0000u); }

// async global->LDS, 16B per lane; LDS dest is wave-uniform base + lane*16.
__device__ __forceinline__ void gload16(const void* g, void* l) {
    __builtin_amdgcn_global_load_lds(
        (const __attribute__((address_space(1))) void*)g,
        (__attribute__((address_space(3))) void*)l, 16, 0, 0);
}

// ---------- K1: prep. blocks 0..63: A colnorm + transpose -> ant (bf16, [m][d]).
//                blocks 64..319: z fp32 -> bf16 copy. (validated R8/R9)
//                block 0 thread 0 also zeroes out[0] (mega accumulates atomically). ----
__global__ __launch_bounds__(256) void prep_kernel(const float* __restrict__ A,
                                                   const float* __restrict__ z,
                                                   ushort* __restrict__ zb,
                                                   ushort* __restrict__ ant,
                                                   float* __restrict__ out) {
    const int bid = blockIdx.x;
    const int tid = threadIdx.x;

    if (bid >= 64) {                       // ---- zconv: 256 blocks x 8192 floats ----
        const size_t base = (size_t)(bid - 64) * 8192 + tid * 8;
#pragma unroll
        for (int j = 0; j < 4; ++j) {
            const size_t i = base + j * 2048;
            const float4 a = *reinterpret_cast<const float4*>(&z[i]);
            const float4 b = *reinterpret_cast<const float4*>(&z[i + 4]);
            uint4 p;
            p.x = (unsigned)f2bf(a.x) | ((unsigned)f2bf(a.y) << 16);
            p.y = (unsigned)f2bf(a.z) | ((unsigned)f2bf(a.w) << 16);
            p.z = (unsigned)f2bf(b.x) | ((unsigned)f2bf(b.y) << 16);
            p.w = (unsigned)f2bf(b.z) | ((unsigned)f2bf(b.w) << 16);
            *reinterpret_cast<uint4*>(&zb[i]) = p;
        }
        return;
    }

    if (bid == 0 && tid == 0) out[0] = 0.0f;   // reset accumulator (runs before mega)

    __shared__ float red[256];
    __shared__ float inv[16];
    __shared__ float tile[128][17];

    const int mB = bid * 16;
    const int mo = tid & 15;
    const int dg = tid >> 4;
    float ss = 0.0f;
#pragma unroll 4
    for (int i = 0; i < 32; ++i) {
        const float v = A[(size_t)(dg * 32 + i) * M_DIM + mB + mo];
        ss = fmaf(v, v, ss);
    }
    red[tid] = ss;
    __syncthreads();
    for (int s = 128; s >= 16; s >>= 1) {
        if (tid < s) red[tid] += red[tid + s];
        __syncthreads();
    }
    if (tid < 16) inv[tid] = 1.0f / fmaxf(sqrtf(red[tid]), 1e-12f);

#pragma unroll
    for (int ch = 0; ch < 4; ++ch) {
        const int dB = ch * 128;
#pragma unroll
        for (int q = 0; q < 2; ++q) {
            const int s  = tid + 256 * q;
            const int r  = s >> 2;
            const int c4 = (s & 3) * 4;
            const float4 v = *reinterpret_cast<const float4*>(
                &A[(size_t)(dB + r) * M_DIM + mB + c4]);
            tile[r][c4]     = v.x;
            tile[r][c4 + 1] = v.y;
            tile[r][c4 + 2] = v.z;
            tile[r][c4 + 3] = v.w;
        }
        __syncthreads();
        {
            const int m  = tid >> 4;
            const int d8 = (tid & 15) * 8;
            const float sc = inv[m];
            uint4 p;
            p.x = (unsigned)f2bf(tile[d8 + 0][m] * sc) | ((unsigned)f2bf(tile[d8 + 1][m] * sc) << 16);
            p.y = (unsigned)f2bf(tile[d8 + 2][m] * sc) | ((unsigned)f2bf(tile[d8 + 3][m] * sc) << 16);
            p.z = (unsigned)f2bf(tile[d8 + 4][m] * sc) | ((unsigned)f2bf(tile[d8 + 5][m] * sc) << 16);
            p.w = (unsigned)f2bf(tile[d8 + 6][m] * sc) | ((unsigned)f2bf(tile[d8 + 7][m] * sc) << 16);
            *reinterpret_cast<uint4*>(&ant[(size_t)(mB + m) * D_DIM + dB + d8]) = p;
        }
        __syncthreads();
    }
}

// ---------- K2: MEGA — bf16 MFMA GEMM (m97 structure) -> LDS tile -> CF stat -> atomicAdd ----
// grid (M/128=8, T=32), 256 thr. GEMM part & epilogue layout validated R9 (absmax 0);
// stat math validated R8/R9 (k-on-threads, 2 accumulators).
__global__ __launch_bounds__(256) void mega_kernel(const ushort* __restrict__ zb,
                                                   const ushort* __restrict__ ant,
                                                   float* __restrict__ out) {
    __shared__ __align__(16) union {
        struct { ushort As[128 * 64]; ushort Bs[128 * 64]; } g;   // 32 KB (GEMM phase)
        ushort tile[128][136];                                    // 34 KB (stat phase) [m][b]
    } u;
    __shared__ float sred[4];

    const int tid    = threadIdx.x;
    const int colBlk = blockIdx.x * 128;   // m
    const int rowBlk = blockIdx.y * 128;   // b-rows = one t
    const int wave = tid >> 6;
    const int lane = tid & 63;
    const int wr   = wave >> 1;
    const int wc   = wave & 1;
    const int l15  = lane & 15;
    const int lhi  = lane >> 4;

    const int l8 = lane >> 3;              // 0..7  (row within 8-row group)
    const int c8 = (lane & 7) * 8;         // elem col within BK

    f32x4 acc[4][4];
#pragma unroll
    for (int fm = 0; fm < 4; ++fm)
#pragma unroll
        for (int fn = 0; fn < 4; ++fn) acc[fm][fn] = (f32x4)(0.0f);

#pragma unroll
    for (int it = 0; it < 8; ++it) {
        const int k0 = it * 64;
#pragma unroll
        for (int j = 0; j < 4; ++j) {
            const int r = wave * 32 + j * 8;
            gload16(&zb[(size_t)(rowBlk + r + l8) * D_DIM + k0 + c8], &u.g.As[r * 64]);
            gload16(&ant[(size_t)(colBlk + r + l8) * D_DIM + k0 + c8], &u.g.Bs[r * 64]);
        }
        __syncthreads();                   // drains vmcnt -> LDS data visible

#pragma unroll
        for (int ks = 0; ks < 2; ++ks) {
            bf16x8 af[4], bfr[4];
#pragma unroll
            for (int fm = 0; fm < 4; ++fm)
                af[fm] = *reinterpret_cast<const bf16x8*>(&u.g.As[(wr * 64 + fm * 16 + l15) * 64 + ks * 32 + lhi * 8]);
#pragma unroll
            for (int fn = 0; fn < 4; ++fn)
                bfr[fn] = *reinterpret_cast<const bf16x8*>(&u.g.Bs[(wc * 64 + fn * 16 + l15) * 64 + ks * 32 + lhi * 8]);
#pragma unroll
            for (int fm = 0; fm < 4; ++fm)
#pragma unroll
                for (int fn = 0; fn < 4; ++fn)
                    acc[fm][fn] = __builtin_amdgcn_mfma_f32_16x16x32_bf16(af[fm], bfr[fn], acc[fm][fn], 0, 0, 0);
        }
        __syncthreads();                   // readers done before next-iter overwrite
    }
    // last barrier above: As/Bs now dead -> safe to overwrite with tile

    // epilogue -> LDS: col=l15 -> m (block-local), row=lhi*4+reg -> b (block-local)
#pragma unroll
    for (int fn = 0; fn < 4; ++fn) {
        const int m = wc * 64 + fn * 16 + l15;
#pragma unroll
        for (int fm = 0; fm < 4; ++fm) {
            const int b = wr * 64 + fm * 16 + lhi * 4;
            u.tile[m][b + 0] = f2bf(acc[fm][fn][0]);
            u.tile[m][b + 1] = f2bf(acc[fm][fn][1]);
            u.tile[m][b + 2] = f2bf(acc[fm][fn][2]);
            u.tile[m][b + 3] = f2bf(acc[fm][fn][3]);
        }
    }
    __syncthreads();

    // ---- CF stat: thread = (m in 16-group, knot k); 8 m's per thread, same k ----
    const int ml0 = tid & 15;
    const int kk  = (tid >> 4) + 1;        // 1..16 (knot 0 contributes exactly 0)
    const float kf   = (float)kk * (DT * INV_2PI);
    const float tk   = (float)kk * DT;
    const float gk   = __expf(-0.5f * tk * tk);
    const float wk   = ((kk == 16) ? DT : 2.0f * DT) * gk;
    const float invB = 1.0f / 128.0f;

    float e = 0.0f;
#pragma unroll
    for (int j = 0; j < 8; ++j) {
        const int m = ml0 + 16 * j;
        float ca = 0.0f, sa = 0.0f;
#pragma unroll 4
        for (int b0 = 0; b0 < 128; b0 += 8) {
            const uint4 v = *reinterpret_cast<const uint4*>(&u.tile[m][b0]);   // ds_read_b128
            const float x0 = bf_lo(v.x), x1 = bf_hi(v.x), x2 = bf_lo(v.y), x3 = bf_hi(v.y);
            const float x4 = bf_lo(v.z), x5 = bf_hi(v.z), x6 = bf_lo(v.w), x7 = bf_hi(v.w);
            float a, r;
            a = x0 * kf; r = a - floorf(a); sa += __builtin_amdgcn_sinf(r); ca += __builtin_amdgcn_cosf(r);
            a = x1 * kf; r = a - floorf(a); sa += __builtin_amdgcn_sinf(r); ca += __builtin_amdgcn_cosf(r);
            a = x2 * kf; r = a - floorf(a); sa += __builtin_amdgcn_sinf(r); ca += __builtin_amdgcn_cosf(r);
            a = x3 * kf; r = a - floorf(a); sa += __builtin_amdgcn_sinf(r); ca += __builtin_amdgcn_cosf(r);
            a = x4 * kf; r = a - floorf(a); sa += __builtin_amdgcn_sinf(r); ca += __builtin_amdgcn_cosf(r);
            a = x5 * kf; r = a - floorf(a); sa += __builtin_amdgcn_sinf(r); ca += __builtin_amdgcn_cosf(r);
            a = x6 * kf; r = a - floorf(a); sa += __builtin_amdgcn_sinf(r); ca += __builtin_amdgcn_cosf(r);
            a = x7 * kf; r = a - floorf(a); sa += __builtin_amdgcn_sinf(r); ca += __builtin_amdgcn_cosf(r);
        }
        const float cm = fmaf(ca, invB, -gk);
        const float sm = sa * invB;
        e = fmaf(wk, fmaf(cm, cm, sm * sm), e);
    }

    // block reduce + one atomic per block; out = sum_blocks(blocksum)/256
#pragma unroll
    for (int msk = 1; msk < 64; msk <<= 1) e += __shfl_xor(e, msk);
    if (lane == 0) sred[wave] = e;
    __syncthreads();
    if (tid == 0)
        atomicAdd(out, (sred[0] + sred[1] + sred[2] + sred[3]) * (1.0f / 256.0f));
}

extern "C" void kernel_launch(void* const* d_in, const int* in_sizes, int n_in,
                              void* d_out, int out_size, void* d_ws, size_t ws_size,
                              hipStream_t stream) {
    const float* z = (const float*)d_in[0];   // (32,128,512)
    const float* A = (const float*)d_in[1];   // (512,1024)
    float* out = (float*)d_out;

    char* ws = (char*)d_ws;
    ushort* zb  = (ushort*)ws;                        // 4 MB
    ushort* ant = (ushort*)(ws + 4 * 1024 * 1024);    // 1 MB

    prep_kernel<<<320, 256, 0, stream>>>(A, z, zb, ant, out);
    mega_kernel<<<dim3(M_DIM / 128, T_DIM), 256, 0, stream>>>(zb, ant, out);
}

// Round 11
// 45.888 us; speedup vs baseline: 1.3077x; 1.0259x over previous
//
#include <hip/hip_runtime.h>
#include <hip/hip_bf16.h>
#include <math.h>

#define T_DIM 32
#define B_DIM 128
#define D_DIM 512
#define M_DIM 1024
#define R_DIM (T_DIM * B_DIM)          // 4096 proj rows

constexpr float DT = 0.1875f;          // 3.0 / 16
constexpr float INV_2PI = 0.15915494309189535f;

typedef __attribute__((ext_vector_type(8))) short bf16x8;   // 8 bf16 = 4 VGPR
typedef __attribute__((ext_vector_type(4))) float f32x4;    // MFMA acc
typedef __attribute__((ext_vector_type(2))) float f32x2;    // packed (cos,sin)

__device__ __forceinline__ ushort f2bf(float f) {           // RNE fp32->bf16
    unsigned u = __float_as_uint(f);
    u += 0x7FFFu + ((u >> 16) & 1u);
    return (ushort)(u >> 16);
}
__device__ __forceinline__ float bf_lo(unsigned u) { return __uint_as_float(u << 16); }
__device__ __forceinline__ float bf_hi(unsigned u) { return __uint_as_float(u & 0xFFFF0000u); }

// async global->LDS, 16B per lane; LDS dest is wave-uniform base + lane*16.
__device__ __forceinline__ void gload16(const void* g, void* l) {
    __builtin_amdgcn_global_load_lds(
        (const __attribute__((address_space(1))) void*)g,
        (__attribute__((address_space(3))) void*)l, 16, 0, 0);
}

// v_sin/v_cos take REVOLUTIONS (ISA: D=sin(S0*2pi)); reduce with floor.
__device__ __forceinline__ void fast_sincos(float theta, float& s, float& c) {
    float r = theta * INV_2PI;
    r -= floorf(r);
    s = __builtin_amdgcn_sinf(r);
    c = __builtin_amdgcn_cosf(r);
}

// ---------- K1: prep (validated R8-R10). blocks 0..63: colnorm+transpose -> ant.
//                blocks 64..319: z -> bf16. block 0 zeroes out[0]. ----------
__global__ __launch_bounds__(256) void prep_kernel(const float* __restrict__ A,
                                                   const float* __restrict__ z,
                                                   ushort* __restrict__ zb,
                                                   ushort* __restrict__ ant,
                                                   float* __restrict__ out) {
    const int bid = blockIdx.x;
    const int tid = threadIdx.x;

    if (bid >= 64) {                       // ---- zconv: 256 blocks x 8192 floats ----
        const size_t base = (size_t)(bid - 64) * 8192 + tid * 8;
#pragma unroll
        for (int j = 0; j < 4; ++j) {
            const size_t i = base + j * 2048;
            const float4 a = *reinterpret_cast<const float4*>(&z[i]);
            const float4 b = *reinterpret_cast<const float4*>(&z[i + 4]);
            uint4 p;
            p.x = (unsigned)f2bf(a.x) | ((unsigned)f2bf(a.y) << 16);
            p.y = (unsigned)f2bf(a.z) | ((unsigned)f2bf(a.w) << 16);
            p.z = (unsigned)f2bf(b.x) | ((unsigned)f2bf(b.y) << 16);
            p.w = (unsigned)f2bf(b.z) | ((unsigned)f2bf(b.w) << 16);
            *reinterpret_cast<uint4*>(&zb[i]) = p;
        }
        return;
    }

    if (bid == 0 && tid == 0) out[0] = 0.0f;   // reset accumulator for atomics

    __shared__ float red[256];
    __shared__ float inv[16];
    __shared__ float tile[128][17];

    const int mB = bid * 16;
    const int mo = tid & 15;
    const int dg = tid >> 4;
    float ss = 0.0f;
#pragma unroll 4
    for (int i = 0; i < 32; ++i) {
        const float v = A[(size_t)(dg * 32 + i) * M_DIM + mB + mo];
        ss = fmaf(v, v, ss);
    }
    red[tid] = ss;
    __syncthreads();
    for (int s = 128; s >= 16; s >>= 1) {
        if (tid < s) red[tid] += red[tid + s];
        __syncthreads();
    }
    if (tid < 16) inv[tid] = 1.0f / fmaxf(sqrtf(red[tid]), 1e-12f);

#pragma unroll
    for (int ch = 0; ch < 4; ++ch) {
        const int dB = ch * 128;
#pragma unroll
        for (int q = 0; q < 2; ++q) {
            const int s  = tid + 256 * q;
            const int r  = s >> 2;
            const int c4 = (s & 3) * 4;
            const float4 v = *reinterpret_cast<const float4*>(
                &A[(size_t)(dB + r) * M_DIM + mB + c4]);
            tile[r][c4]     = v.x;
            tile[r][c4 + 1] = v.y;
            tile[r][c4 + 2] = v.z;
            tile[r][c4 + 3] = v.w;
        }
        __syncthreads();
        {
            const int m  = tid >> 4;
            const int d8 = (tid & 15) * 8;
            const float sc = inv[m];
            uint4 p;
            p.x = (unsigned)f2bf(tile[d8 + 0][m] * sc) | ((unsigned)f2bf(tile[d8 + 1][m] * sc) << 16);
            p.y = (unsigned)f2bf(tile[d8 + 2][m] * sc) | ((unsigned)f2bf(tile[d8 + 3][m] * sc) << 16);
            p.z = (unsigned)f2bf(tile[d8 + 4][m] * sc) | ((unsigned)f2bf(tile[d8 + 5][m] * sc) << 16);
            p.w = (unsigned)f2bf(tile[d8 + 6][m] * sc) | ((unsigned)f2bf(tile[d8 + 7][m] * sc) << 16);
            *reinterpret_cast<uint4*>(&ant[(size_t)(mB + m) * D_DIM + dB + d8]) = p;
        }
        __syncthreads();
    }
}

// ---------- K2: bf16 MFMA GEMM via global_load_lds -> proj_cm ([M][R] bf16) ----------
// (validated R9: absmax 0). 128x128 tile, BK=64, linear LDS, 2-barrier loop.
__global__ __launch_bounds__(256) void gemm_kernel(const ushort* __restrict__ zb,
                                                   const ushort* __restrict__ ant,
                                                   ushort* __restrict__ proj_cm) {
    __shared__ __align__(16) ushort As[128 * 64];
    __shared__ __align__(16) ushort Bs[128 * 64];

    const int tid    = threadIdx.x;
    const int colBlk = blockIdx.x * 128;   // m
    const int rowBlk = blockIdx.y * 128;   // b-rows = one t
    const int wave = tid >> 6;
    const int lane = tid & 63;
    const int wr   = wave >> 1;
    const int wc   = wave & 1;
    const int l15  = lane & 15;
    const int lhi  = lane >> 4;

    const int l8 = lane >> 3;
    const int c8 = (lane & 7) * 8;

    f32x4 acc[4][4];
#pragma unroll
    for (int fm = 0; fm < 4; ++fm)
#pragma unroll
        for (int fn = 0; fn < 4; ++fn) acc[fm][fn] = (f32x4)(0.0f);

#pragma unroll
    for (int it = 0; it < 8; ++it) {
        const int k0 = it * 64;
#pragma unroll
        for (int j = 0; j < 4; ++j) {
            const int r = wave * 32 + j * 8;
            gload16(&zb[(size_t)(rowBlk + r + l8) * D_DIM + k0 + c8], &As[r * 64]);
            gload16(&ant[(size_t)(colBlk + r + l8) * D_DIM + k0 + c8], &Bs[r * 64]);
        }
        __syncthreads();

#pragma unroll
        for (int ks = 0; ks < 2; ++ks) {
            bf16x8 af[4], bfr[4];
#pragma unroll
            for (int fm = 0; fm < 4; ++fm)
                af[fm] = *reinterpret_cast<const bf16x8*>(&As[(wr * 64 + fm * 16 + l15) * 64 + ks * 32 + lhi * 8]);
#pragma unroll
            for (int fn = 0; fn < 4; ++fn)
                bfr[fn] = *reinterpret_cast<const bf16x8*>(&Bs[(wc * 64 + fn * 16 + l15) * 64 + ks * 32 + lhi * 8]);
#pragma unroll
            for (int fm = 0; fm < 4; ++fm)
#pragma unroll
                for (int fn = 0; fn < 4; ++fn)
                    acc[fm][fn] = __builtin_amdgcn_mfma_f32_16x16x32_bf16(af[fm], bfr[fn], acc[fm][fn], 0, 0, 0);
        }
        __syncthreads();
    }

#pragma unroll
    for (int fn = 0; fn < 4; ++fn) {
        const int m = colBlk + wc * 64 + fn * 16 + l15;
#pragma unroll
        for (int fm = 0; fm < 4; ++fm) {
            const int r0 = rowBlk + wr * 64 + fm * 16 + lhi * 4;
            ushort4 o;
            o.x = f2bf(acc[fm][fn][0]);
            o.y = f2bf(acc[fm][fn][1]);
            o.z = f2bf(acc[fm][fn][2]);
            o.w = f2bf(acc[fm][fn][3]);
            *reinterpret_cast<ushort4*>(&proj_cm[(size_t)m * R_DIM + r0]) = o;
        }
    }
}

// ---------- K3: CF stat, Chebyshev, high occupancy ----------
// grid (32 mchunks, 32 t) = 1024 blocks (4/CU). thread = (m 0..31, bq 0..7), 16 elems.
#define CHEB(CS) { const f32x2 nxt = c2 * cur - prev; prev = cur; cur = nxt; CS += cur; }
#define CF_ALL(V) { \
    float s1, c1; fast_sincos((V) * DT, s1, c1); \
    const float c2 = 2.0f * c1; \
    f32x2 prev = {1.0f, 0.0f}; \
    f32x2 cur  = {c1, s1}; \
    cs0 += cur; \
    CHEB(cs1)  CHEB(cs2)  CHEB(cs3)  CHEB(cs4)  CHEB(cs5) \
    CHEB(cs6)  CHEB(cs7)  CHEB(cs8)  CHEB(cs9)  CHEB(cs10) \
    CHEB(cs11) CHEB(cs12) CHEB(cs13) CHEB(cs14) CHEB(cs15) }
#define RED32(CS) { CS.x += __shfl_xor(CS.x, 32); CS.y += __shfl_xor(CS.y, 32); }
#define STW(CS, K) { wred[wave][lane][K] = CS; }

__global__ __launch_bounds__(256, 4) void stat_kernel(const ushort* __restrict__ proj_cm,
                                                      float* __restrict__ out) {
    __shared__ float tile[32][133];     // [m][b], stride 133: conflict-free reads
    __shared__ f32x2 wred[4][32][17];   // [wave][m][k], padded
    __shared__ float sred[4];

    const int tid = threadIdx.x;
    const int mB  = blockIdx.x * 32;    // 32 chunks
    const int t   = blockIdx.y;         // 32
    const int wave = tid >> 6;
    const int lane = tid & 63;

    {   // stage: 32 m x 128 b, bf16 -> f32; 8 threads/row x 16 b each
        const int m  = tid >> 3;
        const int b0 = (tid & 7) * 16;
        const ushort* src = &proj_cm[(size_t)(mB + m) * R_DIM + t * B_DIM + b0];
        const uint4 v0 = *reinterpret_cast<const uint4*>(src);
        const uint4 v1 = *reinterpret_cast<const uint4*>(src + 8);
        float* d = &tile[m][b0];
        d[0] = bf_lo(v0.x); d[1] = bf_hi(v0.x); d[2] = bf_lo(v0.y); d[3] = bf_hi(v0.y);
        d[4] = bf_lo(v0.z); d[5] = bf_hi(v0.z); d[6] = bf_lo(v0.w); d[7] = bf_hi(v0.w);
        d[8]  = bf_lo(v1.x); d[9]  = bf_hi(v1.x); d[10] = bf_lo(v1.y); d[11] = bf_hi(v1.y);
        d[12] = bf_lo(v1.z); d[13] = bf_hi(v1.z); d[14] = bf_lo(v1.w); d[15] = bf_hi(v1.w);
    }
    __syncthreads();

    const int m  = tid & 31;
    const int bq = tid >> 5;            // 0..7 (16 b's each)

    f32x2 cs0  = {0.f, 0.f}, cs1  = {0.f, 0.f}, cs2  = {0.f, 0.f}, cs3  = {0.f, 0.f};
    f32x2 cs4  = {0.f, 0.f}, cs5  = {0.f, 0.f}, cs6  = {0.f, 0.f}, cs7  = {0.f, 0.f};
    f32x2 cs8  = {0.f, 0.f}, cs9  = {0.f, 0.f}, cs10 = {0.f, 0.f}, cs11 = {0.f, 0.f};
    f32x2 cs12 = {0.f, 0.f}, cs13 = {0.f, 0.f}, cs14 = {0.f, 0.f}, cs15 = {0.f, 0.f};

#pragma unroll
    for (int i = 0; i < 16; ++i) {
        const float x = tile[m][bq * 16 + i];
        CF_ALL(x)
    }

    // lane l and l+32 share m, differ in bq -> xor-32 folds them
    RED32(cs0)  RED32(cs1)  RED32(cs2)  RED32(cs3)
    RED32(cs4)  RED32(cs5)  RED32(cs6)  RED32(cs7)
    RED32(cs8)  RED32(cs9)  RED32(cs10) RED32(cs11)
    RED32(cs12) RED32(cs13) RED32(cs14) RED32(cs15)

    if (lane < 32) {
        STW(cs0, 0)   STW(cs1, 1)   STW(cs2, 2)   STW(cs3, 3)
        STW(cs4, 4)   STW(cs5, 5)   STW(cs6, 6)   STW(cs7, 7)
        STW(cs8, 8)   STW(cs9, 9)   STW(cs10, 10) STW(cs11, 11)
        STW(cs12, 12) STW(cs13, 13) STW(cs14, 14) STW(cs15, 15)
    }
    __syncthreads();

    // final: 512 (m,k) slots, 2 per thread
    const float invB = 1.0f / 128.0f;
    float e = 0.0f;
#pragma unroll
    for (int it = 0; it < 2; ++it) {
        const int j  = tid + 256 * it;     // 0..511
        const int mm = j & 31;
        const int k  = j >> 5;             // 0..15 -> knot k+1
        const f32x2 s4 = wred[0][mm][k] + wred[1][mm][k] + wred[2][mm][k] + wred[3][mm][k];
        const float tk = DT * (float)(k + 1);
        const float g  = __expf(-0.5f * tk * tk);
        const float wg = ((k == 15) ? DT : 2.0f * DT) * g;
        const float cm = fmaf(s4.x, invB, -g);
        const float sm = s4.y * invB;
        e = fmaf(wg, fmaf(cm, cm, sm * sm), e);
    }

#pragma unroll
    for (int msk = 1; msk < 64; msk <<= 1) e += __shfl_xor(e, msk);
    if (lane == 0) sred[wave] = e;
    __syncthreads();
    if (tid == 0)
        atomicAdd(out, (sred[0] + sred[1] + sred[2] + sred[3]) * (1.0f / 256.0f));
}

extern "C" void kernel_launch(void* const* d_in, const int* in_sizes, int n_in,
                              void* d_out, int out_size, void* d_ws, size_t ws_size,
                              hipStream_t stream) {
    const float* z = (const float*)d_in[0];   // (32,128,512)
    const float* A = (const float*)d_in[1];   // (512,1024)
    float* out = (float*)d_out;

    char* ws = (char*)d_ws;
    ushort* zb      = (ushort*)ws;                        // 4 MB
    ushort* ant     = (ushort*)(ws + 4 * 1024 * 1024);    // 1 MB
    ushort* proj_cm = (ushort*)(ws + 5 * 1024 * 1024);    // 8 MB

    prep_kernel<<<320, 256, 0, stream>>>(A, z, zb, ant, out);
    gemm_kernel<<<dim3(M_DIM / 128, T_DIM), 256, 0, stream>>>(zb, ant, proj_cm);
    stat_kernel<<<dim3(32, T_DIM), 256, 0, stream>>>(proj_cm, out);
}

// Round 12
// 44.596 us; speedup vs baseline: 1.3456x; 1.0290x over previous
//
#include <hip/hip_runtime.h>
#include <hip/hip_bf16.h>
#include <math.h>

#define T_DIM 32
#define B_DIM 128
#define D_DIM 512
#define M_DIM 1024
#define R_DIM (T_DIM * B_DIM)          // 4096 proj rows

constexpr float DT = 0.1875f;          // 3.0 / 16
constexpr float INV_2PI = 0.15915494309189535f;

typedef __attribute__((ext_vector_type(8))) short bf16x8;   // 8 bf16 = 4 VGPR
typedef __attribute__((ext_vector_type(4))) float f32x4;    // MFMA acc
typedef __attribute__((ext_vector_type(2))) float f32x2;    // packed (cos,sin)

__device__ __forceinline__ ushort f2bf(float f) {           // RNE fp32->bf16
    unsigned u = __float_as_uint(f);
    u += 0x7FFFu + ((u >> 16) & 1u);
    return (ushort)(u >> 16);
}
__device__ __forceinline__ float bf_lo(unsigned u) { return __uint_as_float(u << 16); }
__device__ __forceinline__ float bf_hi(unsigned u) { return __uint_as_float(u & 0xFFFF0000u); }

// async global->LDS, 16B per lane; LDS dest is wave-uniform base + lane*16.
__device__ __forceinline__ void gload16(const void* g, void* l) {
    __builtin_amdgcn_global_load_lds(
        (const __attribute__((address_space(1))) void*)g,
        (__attribute__((address_space(3))) void*)l, 16, 0, 0);
}

// v_sin/v_cos take REVOLUTIONS (ISA: D=sin(S0*2pi)); reduce with floor.
__device__ __forceinline__ void fast_sincos(float theta, float& s, float& c) {
    float r = theta * INV_2PI;
    r -= floorf(r);
    s = __builtin_amdgcn_sinf(r);
    c = __builtin_amdgcn_cosf(r);
}

// ---------- K1: prep (validated R8-R11). blocks 0..63: colnorm+transpose -> ant.
//                blocks 64..319: z -> bf16. block 0 zeroes out[0]. ----------
__global__ __launch_bounds__(256) void prep_kernel(const float* __restrict__ A,
                                                   const float* __restrict__ z,
                                                   ushort* __restrict__ zb,
                                                   ushort* __restrict__ ant,
                                                   float* __restrict__ out) {
    const int bid = blockIdx.x;
    const int tid = threadIdx.x;

    if (bid >= 64) {                       // ---- zconv: 256 blocks x 8192 floats ----
        const size_t base = (size_t)(bid - 64) * 8192 + tid * 8;
#pragma unroll
        for (int j = 0; j < 4; ++j) {
            const size_t i = base + j * 2048;
            const float4 a = *reinterpret_cast<const float4*>(&z[i]);
            const float4 b = *reinterpret_cast<const float4*>(&z[i + 4]);
            uint4 p;
            p.x = (unsigned)f2bf(a.x) | ((unsigned)f2bf(a.y) << 16);
            p.y = (unsigned)f2bf(a.z) | ((unsigned)f2bf(a.w) << 16);
            p.z = (unsigned)f2bf(b.x) | ((unsigned)f2bf(b.y) << 16);
            p.w = (unsigned)f2bf(b.z) | ((unsigned)f2bf(b.w) << 16);
            *reinterpret_cast<uint4*>(&zb[i]) = p;
        }
        return;
    }

    if (bid == 0 && tid == 0) out[0] = 0.0f;   // reset accumulator for atomics

    __shared__ float red[256];
    __shared__ float inv[16];
    __shared__ float tile[128][17];

    const int mB = bid * 16;
    const int mo = tid & 15;
    const int dg = tid >> 4;
    float ss = 0.0f;
#pragma unroll 4
    for (int i = 0; i < 32; ++i) {
        const float v = A[(size_t)(dg * 32 + i) * M_DIM + mB + mo];
        ss = fmaf(v, v, ss);
    }
    red[tid] = ss;
    __syncthreads();
    for (int s = 128; s >= 16; s >>= 1) {
        if (tid < s) red[tid] += red[tid + s];
        __syncthreads();
    }
    if (tid < 16) inv[tid] = 1.0f / fmaxf(sqrtf(red[tid]), 1e-12f);

#pragma unroll
    for (int ch = 0; ch < 4; ++ch) {
        const int dB = ch * 128;
#pragma unroll
        for (int q = 0; q < 2; ++q) {
            const int s  = tid + 256 * q;
            const int r  = s >> 2;
            const int c4 = (s & 3) * 4;
            const float4 v = *reinterpret_cast<const float4*>(
                &A[(size_t)(dB + r) * M_DIM + mB + c4]);
            tile[r][c4]     = v.x;
            tile[r][c4 + 1] = v.y;
            tile[r][c4 + 2] = v.z;
            tile[r][c4 + 3] = v.w;
        }
        __syncthreads();
        {
            const int m  = tid >> 4;
            const int d8 = (tid & 15) * 8;
            const float sc = inv[m];
            uint4 p;
            p.x = (unsigned)f2bf(tile[d8 + 0][m] * sc) | ((unsigned)f2bf(tile[d8 + 1][m] * sc) << 16);
            p.y = (unsigned)f2bf(tile[d8 + 2][m] * sc) | ((unsigned)f2bf(tile[d8 + 3][m] * sc) << 16);
            p.z = (unsigned)f2bf(tile[d8 + 4][m] * sc) | ((unsigned)f2bf(tile[d8 + 5][m] * sc) << 16);
            p.w = (unsigned)f2bf(tile[d8 + 6][m] * sc) | ((unsigned)f2bf(tile[d8 + 7][m] * sc) << 16);
            *reinterpret_cast<uint4*>(&ant[(size_t)(mB + m) * D_DIM + dB + d8]) = p;
        }
        __syncthreads();
    }
}

// ---------- K2: bf16 MFMA GEMM, 64x64 tile @ 4 blk/CU -> proj_cm ([M][R] bf16) ----------
// grid (16 m-blocks, 64 row-blocks) = 1024 blocks. BK=64, gload16 staging, 2-barrier loop.
// Same fragment/epilogue mapping as validated R9 kernel, halved tile for occupancy.
__global__ __launch_bounds__(256) void gemm_kernel(const ushort* __restrict__ zb,
                                                   const ushort* __restrict__ ant,
                                                   ushort* __restrict__ proj_cm) {
    __shared__ __align__(16) ushort As[64 * 64];   // 8 KB, linear (gload_lds dest)
    __shared__ __align__(16) ushort Bs[64 * 64];

    const int tid    = threadIdx.x;
    const int colBlk = blockIdx.x * 64;    // m  (16)
    const int rowBlk = blockIdx.y * 64;    // b-rows (64)
    const int wave = tid >> 6;
    const int lane = tid & 63;
    const int wr   = wave >> 1;
    const int wc   = wave & 1;
    const int l15  = lane & 15;
    const int lhi  = lane >> 4;

    const int l8 = lane >> 3;              // 0..7 row within 8-row group
    const int c8 = (lane & 7) * 8;         // elem col within BK

    f32x4 acc[2][2];
#pragma unroll
    for (int fm = 0; fm < 2; ++fm)
#pragma unroll
        for (int fn = 0; fn < 2; ++fn) acc[fm][fn] = (f32x4)(0.0f);

#pragma unroll
    for (int it = 0; it < 8; ++it) {
        const int k0 = it * 64;
        // stage: wave w loads A rows w*16..w*16+15 and B rows w*16..w*16+15
#pragma unroll
        for (int j = 0; j < 2; ++j) {
            const int r = wave * 16 + j * 8;
            gload16(&zb[(size_t)(rowBlk + r + l8) * D_DIM + k0 + c8], &As[r * 64]);
            gload16(&ant[(size_t)(colBlk + r + l8) * D_DIM + k0 + c8], &Bs[r * 64]);
        }
        __syncthreads();                   // drains vmcnt -> LDS visible

#pragma unroll
        for (int ks = 0; ks < 2; ++ks) {
            bf16x8 af[2], bfr[2];
#pragma unroll
            for (int fm = 0; fm < 2; ++fm)
                af[fm] = *reinterpret_cast<const bf16x8*>(&As[(wr * 32 + fm * 16 + l15) * 64 + ks * 32 + lhi * 8]);
#pragma unroll
            for (int fn = 0; fn < 2; ++fn)
                bfr[fn] = *reinterpret_cast<const bf16x8*>(&Bs[(wc * 32 + fn * 16 + l15) * 64 + ks * 32 + lhi * 8]);
#pragma unroll
            for (int fm = 0; fm < 2; ++fm)
#pragma unroll
                for (int fn = 0; fn < 2; ++fn)
                    acc[fm][fn] = __builtin_amdgcn_mfma_f32_16x16x32_bf16(af[fm], bfr[fn], acc[fm][fn], 0, 0, 0);
        }
        __syncthreads();                   // readers done before next overwrite
    }

    // epilogue (validated layout): col=l15 -> m, row=lhi*4+reg -> b; 4 regs consecutive.
#pragma unroll
    for (int fn = 0; fn < 2; ++fn) {
        const int m = colBlk + wc * 32 + fn * 16 + l15;
#pragma unroll
        for (int fm = 0; fm < 2; ++fm) {
            const int r0 = rowBlk + wr * 32 + fm * 16 + lhi * 4;
            ushort4 o;
            o.x = f2bf(acc[fm][fn][0]);
            o.y = f2bf(acc[fm][fn][1]);
            o.z = f2bf(acc[fm][fn][2]);
            o.w = f2bf(acc[fm][fn][3]);
            *reinterpret_cast<ushort4*>(&proj_cm[(size_t)m * R_DIM + r0]) = o;
        }
    }
}

// ---------- K3: CF stat, Chebyshev, 4 blk/CU (validated R11) ----------
#define CHEB(CS) { const f32x2 nxt = c2 * cur - prev; prev = cur; cur = nxt; CS += cur; }
#define CF_ALL(V) { \
    float s1, c1; fast_sincos((V) * DT, s1, c1); \
    const float c2 = 2.0f * c1; \
    f32x2 prev = {1.0f, 0.0f}; \
    f32x2 cur  = {c1, s1}; \
    cs0 += cur; \
    CHEB(cs1)  CHEB(cs2)  CHEB(cs3)  CHEB(cs4)  CHEB(cs5) \
    CHEB(cs6)  CHEB(cs7)  CHEB(cs8)  CHEB(cs9)  CHEB(cs10) \
    CHEB(cs11) CHEB(cs12) CHEB(cs13) CHEB(cs14) CHEB(cs15) }
#define RED32(CS) { CS.x += __shfl_xor(CS.x, 32); CS.y += __shfl_xor(CS.y, 32); }
#define STW(CS, K) { wred[wave][lane][K] = CS; }

__global__ __launch_bounds__(256, 4) void stat_kernel(const ushort* __restrict__ proj_cm,
                                                      float* __restrict__ out) {
    __shared__ float tile[32][133];     // [m][b], stride 133: conflict-free reads
    __shared__ f32x2 wred[4][32][17];   // [wave][m][k], padded
    __shared__ float sred[4];

    const int tid = threadIdx.x;
    const int mB  = blockIdx.x * 32;    // 32 chunks
    const int t   = blockIdx.y;         // 32
    const int wave = tid >> 6;
    const int lane = tid & 63;

    {   // stage: 32 m x 128 b, bf16 -> f32; 8 threads/row x 16 b each
        const int m  = tid >> 3;
        const int b0 = (tid & 7) * 16;
        const ushort* src = &proj_cm[(size_t)(mB + m) * R_DIM + t * B_DIM + b0];
        const uint4 v0 = *reinterpret_cast<const uint4*>(src);
        const uint4 v1 = *reinterpret_cast<const uint4*>(src + 8);
        float* d = &tile[m][b0];
        d[0] = bf_lo(v0.x); d[1] = bf_hi(v0.x); d[2] = bf_lo(v0.y); d[3] = bf_hi(v0.y);
        d[4] = bf_lo(v0.z); d[5] = bf_hi(v0.z); d[6] = bf_lo(v0.w); d[7] = bf_hi(v0.w);
        d[8]  = bf_lo(v1.x); d[9]  = bf_hi(v1.x); d[10] = bf_lo(v1.y); d[11] = bf_hi(v1.y);
        d[12] = bf_lo(v1.z); d[13] = bf_hi(v1.z); d[14] = bf_lo(v1.w); d[15] = bf_hi(v1.w);
    }
    __syncthreads();

    const int m  = tid & 31;
    const int bq = tid >> 5;            // 0..7 (16 b's each)

    f32x2 cs0  = {0.f, 0.f}, cs1  = {0.f, 0.f}, cs2  = {0.f, 0.f}, cs3  = {0.f, 0.f};
    f32x2 cs4  = {0.f, 0.f}, cs5  = {0.f, 0.f}, cs6  = {0.f, 0.f}, cs7  = {0.f, 0.f};
    f32x2 cs8  = {0.f, 0.f}, cs9  = {0.f, 0.f}, cs10 = {0.f, 0.f}, cs11 = {0.f, 0.f};
    f32x2 cs12 = {0.f, 0.f}, cs13 = {0.f, 0.f}, cs14 = {0.f, 0.f}, cs15 = {0.f, 0.f};

#pragma unroll
    for (int i = 0; i < 16; ++i) {
        const float x = tile[m][bq * 16 + i];
        CF_ALL(x)
    }

    RED32(cs0)  RED32(cs1)  RED32(cs2)  RED32(cs3)
    RED32(cs4)  RED32(cs5)  RED32(cs6)  RED32(cs7)
    RED32(cs8)  RED32(cs9)  RED32(cs10) RED32(cs11)
    RED32(cs12) RED32(cs13) RED32(cs14) RED32(cs15)

    if (lane < 32) {
        STW(cs0, 0)   STW(cs1, 1)   STW(cs2, 2)   STW(cs3, 3)
        STW(cs4, 4)   STW(cs5, 5)   STW(cs6, 6)   STW(cs7, 7)
        STW(cs8, 8)   STW(cs9, 9)   STW(cs10, 10) STW(cs11, 11)
        STW(cs12, 12) STW(cs13, 13) STW(cs14, 14) STW(cs15, 15)
    }
    __syncthreads();

    const float invB = 1.0f / 128.0f;
    float e = 0.0f;
#pragma unroll
    for (int it = 0; it < 2; ++it) {
        const int j  = tid + 256 * it;     // 0..511
        const int mm = j & 31;
        const int k  = j >> 5;             // 0..15 -> knot k+1
        const f32x2 s4 = wred[0][mm][k] + wred[1][mm][k] + wred[2][mm][k] + wred[3][mm][k];
        const float tk = DT * (float)(k + 1);
        const float g  = __expf(-0.5f * tk * tk);
        const float wg = ((k == 15) ? DT : 2.0f * DT) * g;
        const float cm = fmaf(s4.x, invB, -g);
        const float sm = s4.y * invB;
        e = fmaf(wg, fmaf(cm, cm, sm * sm), e);
    }

#pragma unroll
    for (int msk = 1; msk < 64; msk <<= 1) e += __shfl_xor(e, msk);
    if (lane == 0) sred[wave] = e;
    __syncthreads();
    if (tid == 0)
        atomicAdd(out, (sred[0] + sred[1] + sred[2] + sred[3]) * (1.0f / 256.0f));
}

extern "C" void kernel_launch(void* const* d_in, const int* in_sizes, int n_in,
                              void* d_out, int out_size, void* d_ws, size_t ws_size,
                              hipStream_t stream) {
    const float* z = (const float*)d_in[0];   // (32,128,512)
    const float* A = (const float*)d_in[1];   // (512,1024)
    float* out = (float*)d_out;

    char* ws = (char*)d_ws;
    ushort* zb      = (ushort*)ws;                        // 4 MB
    ushort* ant     = (ushort*)(ws + 4 * 1024 * 1024);    // 1 MB
    ushort* proj_cm = (ushort*)(ws + 5 * 1024 * 1024);    // 8 MB

    prep_kernel<<<320, 256, 0, stream>>>(A, z, zb, ant, out);
    gemm_kernel<<<dim3(M_DIM / 64, R_DIM / 64), 256, 0, stream>>>(zb, ant, proj_cm);
    stat_kernel<<<dim3(32, T_DIM), 256, 0, stream>>>(proj_cm, out);
}

// Round 13
// 41.888 us; speedup vs baseline: 1.4326x; 1.0646x over previous
//
#include <hip/hip_runtime.h>
#include <hip/hip_bf16.h>
#include <math.h>

#define T_DIM 32
#define B_DIM 128
#define D_DIM 512
#define M_DIM 1024
#define R_DIM (T_DIM * B_DIM)          // 4096 proj rows

constexpr float DT = 0.1875f;          // 3.0 / 16
constexpr float INV_2PI = 0.15915494309189535f;

typedef __attribute__((ext_vector_type(8))) short bf16x8;   // 8 bf16 = 4 VGPR
typedef __attribute__((ext_vector_type(4))) float f32x4;    // MFMA acc
typedef __attribute__((ext_vector_type(2))) float f32x2;    // packed (cos,sin)

__device__ __forceinline__ ushort f2bf(float f) {           // RNE fp32->bf16
    unsigned u = __float_as_uint(f);
    u += 0x7FFFu + ((u >> 16) & 1u);
    return (ushort)(u >> 16);
}
__device__ __forceinline__ float bf_lo(unsigned u) { return __uint_as_float(u << 16); }
__device__ __forceinline__ float bf_hi(unsigned u) { return __uint_as_float(u & 0xFFFF0000u); }

// async global->LDS, 16B per lane; LDS dest is wave-uniform base + lane*16.
__device__ __forceinline__ void gload16(const void* g, void* l) {
    __builtin_amdgcn_global_load_lds(
        (const __attribute__((address_space(1))) void*)g,
        (__attribute__((address_space(3))) void*)l, 16, 0, 0);
}

// v_sin/v_cos take REVOLUTIONS (ISA: D=sin(S0*2pi)); reduce with floor.
__device__ __forceinline__ void fast_sincos(float theta, float& s, float& c) {
    float r = theta * INV_2PI;
    r -= floorf(r);
    s = __builtin_amdgcn_sinf(r);
    c = __builtin_amdgcn_cosf(r);
}

// ---------- K1: prep (validated R8-R12). blocks 0..63: colnorm+transpose -> ant.
//                blocks 64..319: z -> bf16. block 0 zeroes out[0]. ----------
__global__ __launch_bounds__(256) void prep_kernel(const float* __restrict__ A,
                                                   const float* __restrict__ z,
                                                   ushort* __restrict__ zb,
                                                   ushort* __restrict__ ant,
                                                   float* __restrict__ out) {
    const int bid = blockIdx.x;
    const int tid = threadIdx.x;

    if (bid >= 64) {                       // ---- zconv: 256 blocks x 8192 floats ----
        const size_t base = (size_t)(bid - 64) * 8192 + tid * 8;
#pragma unroll
        for (int j = 0; j < 4; ++j) {
            const size_t i = base + j * 2048;
            const float4 a = *reinterpret_cast<const float4*>(&z[i]);
            const float4 b = *reinterpret_cast<const float4*>(&z[i + 4]);
            uint4 p;
            p.x = (unsigned)f2bf(a.x) | ((unsigned)f2bf(a.y) << 16);
            p.y = (unsigned)f2bf(a.z) | ((unsigned)f2bf(a.w) << 16);
            p.z = (unsigned)f2bf(b.x) | ((unsigned)f2bf(b.y) << 16);
            p.w = (unsigned)f2bf(b.z) | ((unsigned)f2bf(b.w) << 16);
            *reinterpret_cast<uint4*>(&zb[i]) = p;
        }
        return;
    }

    if (bid == 0 && tid == 0) out[0] = 0.0f;   // reset accumulator for atomics

    __shared__ float red[256];
    __shared__ float inv[16];
    __shared__ float tile[128][17];

    const int mB = bid * 16;
    const int mo = tid & 15;
    const int dg = tid >> 4;
    float ss = 0.0f;
#pragma unroll 4
    for (int i = 0; i < 32; ++i) {
        const float v = A[(size_t)(dg * 32 + i) * M_DIM + mB + mo];
        ss = fmaf(v, v, ss);
    }
    red[tid] = ss;
    __syncthreads();
    for (int s = 128; s >= 16; s >>= 1) {
        if (tid < s) red[tid] += red[tid + s];
        __syncthreads();
    }
    if (tid < 16) inv[tid] = 1.0f / fmaxf(sqrtf(red[tid]), 1e-12f);

#pragma unroll
    for (int ch = 0; ch < 4; ++ch) {
        const int dB = ch * 128;
#pragma unroll
        for (int q = 0; q < 2; ++q) {
            const int s  = tid + 256 * q;
            const int r  = s >> 2;
            const int c4 = (s & 3) * 4;
            const float4 v = *reinterpret_cast<const float4*>(
                &A[(size_t)(dB + r) * M_DIM + mB + c4]);
            tile[r][c4]     = v.x;
            tile[r][c4 + 1] = v.y;
            tile[r][c4 + 2] = v.z;
            tile[r][c4 + 3] = v.w;
        }
        __syncthreads();
        {
            const int m  = tid >> 4;
            const int d8 = (tid & 15) * 8;
            const float sc = inv[m];
            uint4 p;
            p.x = (unsigned)f2bf(tile[d8 + 0][m] * sc) | ((unsigned)f2bf(tile[d8 + 1][m] * sc) << 16);
            p.y = (unsigned)f2bf(tile[d8 + 2][m] * sc) | ((unsigned)f2bf(tile[d8 + 3][m] * sc) << 16);
            p.z = (unsigned)f2bf(tile[d8 + 4][m] * sc) | ((unsigned)f2bf(tile[d8 + 5][m] * sc) << 16);
            p.w = (unsigned)f2bf(tile[d8 + 6][m] * sc) | ((unsigned)f2bf(tile[d8 + 7][m] * sc) << 16);
            *reinterpret_cast<uint4*>(&ant[(size_t)(mB + m) * D_DIM + dB + d8]) = p;
        }
        __syncthreads();
    }
}

// ---------- K2: bf16 MFMA GEMM, 64x64 tile, XOR-swizzled LDS (both-sides) ----------
// Linear [row][64] ushort LDS has row stride 128B = 32 banks -> frag reads were
// 16-way bank-conflicted (lanes read 16 rows at one 16B column). Fix per rule #21:
// gload_lds writes linearly, so PRE-SWIZZLE the global source chunk (lane&7)^l8
// and XOR the read offset with (row&7)*8 ushorts. Each wave read then covers all
// 32 banks (8 slots x 4 banks) = pure-bandwidth 8cyc. MFMA sees identical data.
__global__ __launch_bounds__(256, 4) void gemm_kernel(const ushort* __restrict__ zb,
                                                      const ushort* __restrict__ ant,
                                                      ushort* __restrict__ proj_cm) {
    __shared__ __align__(16) ushort As[64 * 64];   // 8 KB, linear (gload_lds dest)
    __shared__ __align__(16) ushort Bs[64 * 64];

    const int tid    = threadIdx.x;
    const int colBlk = blockIdx.x * 64;    // m  (16)
    const int rowBlk = blockIdx.y * 64;    // b-rows (64)
    const int wave = tid >> 6;
    const int lane = tid & 63;
    const int wr   = wave >> 1;
    const int wc   = wave & 1;
    const int l15  = lane & 15;
    const int lhi  = lane >> 4;

    const int l8 = lane >> 3;              // 0..7 = row within 8-row group = row&7
    const int cx = ((lane & 7) ^ l8) * 8;  // pre-swizzled source k-chunk (ushorts)

    f32x4 acc[2][2];
#pragma unroll
    for (int fm = 0; fm < 2; ++fm)
#pragma unroll
        for (int fn = 0; fn < 2; ++fn) acc[fm][fn] = (f32x4)(0.0f);

    const int swzA = (l15 & 7) * 8;        // read-side XOR (row&7)*8 ushorts

#pragma unroll
    for (int it = 0; it < 8; ++it) {
        const int k0 = it * 64;
        // stage: wave w covers rows w*16..w*16+15 of A and B panels
#pragma unroll
        for (int j = 0; j < 2; ++j) {
            const int r0 = wave * 16 + j * 8;
            gload16(&zb[(size_t)(rowBlk + r0 + l8) * D_DIM + k0 + cx], &As[r0 * 64]);
            gload16(&ant[(size_t)(colBlk + r0 + l8) * D_DIM + k0 + cx], &Bs[r0 * 64]);
        }
        __syncthreads();                   // drains vmcnt -> LDS visible

#pragma unroll
        for (int ks = 0; ks < 2; ++ks) {
            const int co = (ks * 32 + lhi * 8) ^ swzA;   // swizzled column offset
            bf16x8 af[2], bfr[2];
#pragma unroll
            for (int fm = 0; fm < 2; ++fm)
                af[fm] = *reinterpret_cast<const bf16x8*>(&As[(wr * 32 + fm * 16 + l15) * 64 + co]);
#pragma unroll
            for (int fn = 0; fn < 2; ++fn)
                bfr[fn] = *reinterpret_cast<const bf16x8*>(&Bs[(wc * 32 + fn * 16 + l15) * 64 + co]);
#pragma unroll
            for (int fm = 0; fm < 2; ++fm)
#pragma unroll
                for (int fn = 0; fn < 2; ++fn)
                    acc[fm][fn] = __builtin_amdgcn_mfma_f32_16x16x32_bf16(af[fm], bfr[fn], acc[fm][fn], 0, 0, 0);
        }
        __syncthreads();                   // readers done before next overwrite
    }

    // epilogue (validated layout): col=l15 -> m, row=lhi*4+reg -> b; 4 regs consecutive.
#pragma unroll
    for (int fn = 0; fn < 2; ++fn) {
        const int m = colBlk + wc * 32 + fn * 16 + l15;
#pragma unroll
        for (int fm = 0; fm < 2; ++fm) {
            const int r0 = rowBlk + wr * 32 + fm * 16 + lhi * 4;
            ushort4 o;
            o.x = f2bf(acc[fm][fn][0]);
            o.y = f2bf(acc[fm][fn][1]);
            o.z = f2bf(acc[fm][fn][2]);
            o.w = f2bf(acc[fm][fn][3]);
            *reinterpret_cast<ushort4*>(&proj_cm[(size_t)m * R_DIM + r0]) = o;
        }
    }
}

// ---------- K3: CF stat, Chebyshev, 4 blk/CU (validated R11/R12) ----------
#define CHEB(CS) { const f32x2 nxt = c2 * cur - prev; prev = cur; cur = nxt; CS += cur; }
#define CF_ALL(V) { \
    float s1, c1; fast_sincos((V) * DT, s1, c1); \
    const float c2 = 2.0f * c1; \
    f32x2 prev = {1.0f, 0.0f}; \
    f32x2 cur  = {c1, s1}; \
    cs0 += cur; \
    CHEB(cs1)  CHEB(cs2)  CHEB(cs3)  CHEB(cs4)  CHEB(cs5) \
    CHEB(cs6)  CHEB(cs7)  CHEB(cs8)  CHEB(cs9)  CHEB(cs10) \
    CHEB(cs11) CHEB(cs12) CHEB(cs13) CHEB(cs14) CHEB(cs15) }
#define RED32(CS) { CS.x += __shfl_xor(CS.x, 32); CS.y += __shfl_xor(CS.y, 32); }
#define STW(CS, K) { wred[wave][lane][K] = CS; }

__global__ __launch_bounds__(256, 4) void stat_kernel(const ushort* __restrict__ proj_cm,
                                                      float* __restrict__ out) {
    __shared__ float tile[32][133];     // [m][b], stride 133: conflict-free reads
    __shared__ f32x2 wred[4][32][17];   // [wave][m][k], padded
    __shared__ float sred[4];

    const int tid = threadIdx.x;
    const int mB  = blockIdx.x * 32;    // 32 chunks
    const int t   = blockIdx.y;         // 32
    const int wave = tid >> 6;
    const int lane = tid & 63;

    {   // stage: 32 m x 128 b, bf16 -> f32; 8 threads/row x 16 b each
        const int m  = tid >> 3;
        const int b0 = (tid & 7) * 16;
        const ushort* src = &proj_cm[(size_t)(mB + m) * R_DIM + t * B_DIM + b0];
        const uint4 v0 = *reinterpret_cast<const uint4*>(src);
        const uint4 v1 = *reinterpret_cast<const uint4*>(src + 8);
        float* d = &tile[m][b0];
        d[0] = bf_lo(v0.x); d[1] = bf_hi(v0.x); d[2] = bf_lo(v0.y); d[3] = bf_hi(v0.y);
        d[4] = bf_lo(v0.z); d[5] = bf_hi(v0.z); d[6] = bf_lo(v0.w); d[7] = bf_hi(v0.w);
        d[8]  = bf_lo(v1.x); d[9]  = bf_hi(v1.x); d[10] = bf_lo(v1.y); d[11] = bf_hi(v1.y);
        d[12] = bf_lo(v1.z); d[13] = bf_hi(v1.z); d[14] = bf_lo(v1.w); d[15] = bf_hi(v1.w);
    }
    __syncthreads();

    const int m  = tid & 31;
    const int bq = tid >> 5;            // 0..7 (16 b's each)

    f32x2 cs0  = {0.f, 0.f}, cs1  = {0.f, 0.f}, cs2  = {0.f, 0.f}, cs3  = {0.f, 0.f};
    f32x2 cs4  = {0.f, 0.f}, cs5  = {0.f, 0.f}, cs6  = {0.f, 0.f}, cs7  = {0.f, 0.f};
    f32x2 cs8  = {0.f, 0.f}, cs9  = {0.f, 0.f}, cs10 = {0.f, 0.f}, cs11 = {0.f, 0.f};
    f32x2 cs12 = {0.f, 0.f}, cs13 = {0.f, 0.f}, cs14 = {0.f, 0.f}, cs15 = {0.f, 0.f};

#pragma unroll
    for (int i = 0; i < 16; ++i) {
        const float x = tile[m][bq * 16 + i];
        CF_ALL(x)
    }

    RED32(cs0)  RED32(cs1)  RED32(cs2)  RED32(cs3)
    RED32(cs4)  RED32(cs5)  RED32(cs6)  RED32(cs7)
    RED32(cs8)  RED32(cs9)  RED32(cs10) RED32(cs11)
    RED32(cs12) RED32(cs13) RED32(cs14) RED32(cs15)

    if (lane < 32) {
        STW(cs0, 0)   STW(cs1, 1)   STW(cs2, 2)   STW(cs3, 3)
        STW(cs4, 4)   STW(cs5, 5)   STW(cs6, 6)   STW(cs7, 7)
        STW(cs8, 8)   STW(cs9, 9)   STW(cs10, 10) STW(cs11, 11)
        STW(cs12, 12) STW(cs13, 13) STW(cs14, 14) STW(cs15, 15)
    }
    __syncthreads();

    const float invB = 1.0f / 128.0f;
    float e = 0.0f;
#pragma unroll
    for (int it = 0; it < 2; ++it) {
        const int j  = tid + 256 * it;     // 0..511
        const int mm = j & 31;
        const int k  = j >> 5;             // 0..15 -> knot k+1
        const f32x2 s4 = wred[0][mm][k] + wred[1][mm][k] + wred[2][mm][k] + wred[3][mm][k];
        const float tk = DT * (float)(k + 1);
        const float g  = __expf(-0.5f * tk * tk);
        const float wg = ((k == 15) ? DT : 2.0f * DT) * g;
        const float cm = fmaf(s4.x, invB, -g);
        const float sm = s4.y * invB;
        e = fmaf(wg, fmaf(cm, cm, sm * sm), e);
    }

#pragma unroll
    for (int msk = 1; msk < 64; msk <<= 1) e += __shfl_xor(e, msk);
    if (lane == 0) sred[wave] = e;
    __syncthreads();
    if (tid == 0)
        atomicAdd(out, (sred[0] + sred[1] + sred[2] + sred[3]) * (1.0f / 256.0f));
}

extern "C" void kernel_launch(void* const* d_in, const int* in_sizes, int n_in,
                              void* d_out, int out_size, void* d_ws, size_t ws_size,
                              hipStream_t stream) {
    const float* z = (const float*)d_in[0];   // (32,128,512)
    const float* A = (const float*)d_in[1];   // (512,1024)
    float* out = (float*)d_out;

    char* ws = (char*)d_ws;
    ushort* zb      = (ushort*)ws;                        // 4 MB
    ushort* ant     = (ushort*)(ws + 4 * 1024 * 1024);    // 1 MB
    ushort* proj_cm = (ushort*)(ws + 5 * 1024 * 1024);    // 8 MB

    prep_kernel<<<320, 256, 0, stream>>>(A, z, zb, ant, out);
    gemm_kernel<<<dim3(M_DIM / 64, R_DIM / 64), 256, 0, stream>>>(zb, ant, proj_cm);
    stat_kernel<<<dim3(32, T_DIM), 256, 0, stream>>>(proj_cm, out);
}

// Round 14
// 38.277 us; speedup vs baseline: 1.5677x; 1.0943x over previous
//
#include <hip/hip_runtime.h>
#include <hip/hip_bf16.h>
#include <math.h>

#define T_DIM 32
#define B_DIM 128
#define D_DIM 512
#define M_DIM 1024

constexpr float DT = 0.1875f;          // 3.0 / 16
constexpr float INV_2PI = 0.15915494309189535f;

typedef __attribute__((ext_vector_type(8))) short bf16x8;   // 8 bf16 = 4 VGPR
typedef __attribute__((ext_vector_type(4))) float f32x4;    // MFMA acc
typedef __attribute__((ext_vector_type(2))) float f32x2;    // packed (cos,sin)

__device__ __forceinline__ ushort f2bf(float f) {           // RNE fp32->bf16
    unsigned u = __float_as_uint(f);
    u += 0x7FFFu + ((u >> 16) & 1u);
    return (ushort)(u >> 16);
}

// async global->LDS, 16B per lane; LDS dest is wave-uniform base + lane*16.
__device__ __forceinline__ void gload16(const void* g, void* l) {
    __builtin_amdgcn_global_load_lds(
        (const __attribute__((address_space(1))) void*)g,
        (__attribute__((address_space(3))) void*)l, 16, 0, 0);
}

// v_sin/v_cos take REVOLUTIONS (ISA: D=sin(S0*2pi)); reduce with floor.
__device__ __forceinline__ void fast_sincos(float theta, float& s, float& c) {
    float r = theta * INV_2PI;
    r -= floorf(r);
    s = __builtin_amdgcn_sinf(r);
    c = __builtin_amdgcn_cosf(r);
}

// ---------- K1: prep (validated R8-R13). blocks 0..63: colnorm+transpose -> ant.
//                blocks 64..319: z -> bf16. block 0 zeroes out[0]. ----------
__global__ __launch_bounds__(256) void prep_kernel(const float* __restrict__ A,
                                                   const float* __restrict__ z,
                                                   ushort* __restrict__ zb,
                                                   ushort* __restrict__ ant,
                                                   float* __restrict__ out) {
    const int bid = blockIdx.x;
    const int tid = threadIdx.x;

    if (bid >= 64) {                       // ---- zconv: 256 blocks x 8192 floats ----
        const size_t base = (size_t)(bid - 64) * 8192 + tid * 8;
#pragma unroll
        for (int j = 0; j < 4; ++j) {
            const size_t i = base + j * 2048;
            const float4 a = *reinterpret_cast<const float4*>(&z[i]);
            const float4 b = *reinterpret_cast<const float4*>(&z[i + 4]);
            uint4 p;
            p.x = (unsigned)f2bf(a.x) | ((unsigned)f2bf(a.y) << 16);
            p.y = (unsigned)f2bf(a.z) | ((unsigned)f2bf(a.w) << 16);
            p.z = (unsigned)f2bf(b.x) | ((unsigned)f2bf(b.y) << 16);
            p.w = (unsigned)f2bf(b.z) | ((unsigned)f2bf(b.w) << 16);
            *reinterpret_cast<uint4*>(&zb[i]) = p;
        }
        return;
    }

    if (bid == 0 && tid == 0) out[0] = 0.0f;   // reset accumulator for atomics

    __shared__ float red[256];
    __shared__ float inv[16];
    __shared__ float tile[128][17];

    const int mB = bid * 16;
    const int mo = tid & 15;
    const int dg = tid >> 4;
    float ss = 0.0f;
#pragma unroll 4
    for (int i = 0; i < 32; ++i) {
        const float v = A[(size_t)(dg * 32 + i) * M_DIM + mB + mo];
        ss = fmaf(v, v, ss);
    }
    red[tid] = ss;
    __syncthreads();
    for (int s = 128; s >= 16; s >>= 1) {
        if (tid < s) red[tid] += red[tid + s];
        __syncthreads();
    }
    if (tid < 16) inv[tid] = 1.0f / fmaxf(sqrtf(red[tid]), 1e-12f);

#pragma unroll
    for (int ch = 0; ch < 4; ++ch) {
        const int dB = ch * 128;
#pragma unroll
        for (int q = 0; q < 2; ++q) {
            const int s  = tid + 256 * q;
            const int r  = s >> 2;
            const int c4 = (s & 3) * 4;
            const float4 v = *reinterpret_cast<const float4*>(
                &A[(size_t)(dB + r) * M_DIM + mB + c4]);
            tile[r][c4]     = v.x;
            tile[r][c4 + 1] = v.y;
            tile[r][c4 + 2] = v.z;
            tile[r][c4 + 3] = v.w;
        }
        __syncthreads();
        {
            const int m  = tid >> 4;
            const int d8 = (tid & 15) * 8;
            const float sc = inv[m];
            uint4 p;
            p.x = (unsigned)f2bf(tile[d8 + 0][m] * sc) | ((unsigned)f2bf(tile[d8 + 1][m] * sc) << 16);
            p.y = (unsigned)f2bf(tile[d8 + 2][m] * sc) | ((unsigned)f2bf(tile[d8 + 3][m] * sc) << 16);
            p.z = (unsigned)f2bf(tile[d8 + 4][m] * sc) | ((unsigned)f2bf(tile[d8 + 5][m] * sc) << 16);
            p.w = (unsigned)f2bf(tile[d8 + 6][m] * sc) | ((unsigned)f2bf(tile[d8 + 7][m] * sc) << 16);
            *reinterpret_cast<uint4*>(&ant[(size_t)(mB + m) * D_DIM + dB + d8]) = p;
        }
        __syncthreads();
    }
}

// ---------- K2: fused bf16-MFMA GEMM + CF stat ----------
// Tile 128 b-rows x 32 m-cols (full b-range -> in-block CF reduce). grid (32 mBlk, 32 t).
// gload16 + both-sides XOR swizzle (R13). CF = R4's validated Chebyshev epilogue.
// PLAIN launch_bounds(256): no forced VGPR cap (R4-R7's (256,4) cap caused the spill).
#define CHEB(CS) { const f32x2 nxt = c2 * cur - prev; prev = cur; cur = nxt; CS += cur; }
#define CF_ALL(V) { \
    float s1, c1; fast_sincos((V) * DT, s1, c1); \
    const float c2 = 2.0f * c1; \
    f32x2 prev = {1.0f, 0.0f}; \
    f32x2 cur  = {c1, s1}; \
    cs0 += cur; \
    CHEB(cs1)  CHEB(cs2)  CHEB(cs3)  CHEB(cs4)  CHEB(cs5) \
    CHEB(cs6)  CHEB(cs7)  CHEB(cs8)  CHEB(cs9)  CHEB(cs10) \
    CHEB(cs11) CHEB(cs12) CHEB(cs13) CHEB(cs14) CHEB(cs15) }
#define RED(CS) { \
    CS.x += __shfl_xor(CS.x, 16); CS.x += __shfl_xor(CS.x, 32); \
    CS.y += __shfl_xor(CS.y, 16); CS.y += __shfl_xor(CS.y, 32); }
#define ST(CS, K) { wred[wc][l15][K] = CS.x; wred[wc][l15][16 + K] = CS.y; }
#define FIN(CS, KK) { \
    constexpr float tk = DT * (float)(KK); \
    const float g  = __expf(-0.5f * tk * tk); \
    const float w  = (((KK) == 16) ? DT : 2.0f * DT) * g; \
    const float totC = wred[wc][l15][(KK) - 1]      + CS.x; \
    const float totS = wred[wc][l15][16 + (KK) - 1] + CS.y; \
    const float cm = fmaf(totC, invB, -g); \
    const float sm = totS * invB; \
    s = fmaf(w, fmaf(cm, cm, sm * sm), s); }

__global__ __launch_bounds__(256) void fused_kernel(const ushort* __restrict__ zb,
                                                    const ushort* __restrict__ ant,
                                                    float* __restrict__ out) {
    __shared__ __align__(16) ushort As[128 * 64];   // 16 KB linear (gload_lds dest)
    __shared__ __align__(16) ushort Bs[32 * 64];    // 4 KB
    __shared__ float wred[2][16][33];               // [wc][m][k | 16+k], padded
    __shared__ float bred[2];

    const int tid  = threadIdx.x;
    const int mB   = blockIdx.x * 32;               // 32 m-blocks
    const int t    = blockIdx.y;                    // 0..31
    const int wave = tid >> 6;
    const int lane = tid & 63;
    const int wr   = wave >> 1;                     // b-row half
    const int wc   = wave & 1;                      // m-col half
    const int l15  = lane & 15;
    const int lhi  = lane >> 4;

    const int l8 = lane >> 3;              // 0..7 = dest row & 7
    const int cx = ((lane & 7) ^ l8) * 8;  // pre-swizzled source k-chunk

    const ushort* zrow = zb + (size_t)t * B_DIM * D_DIM;

    f32x4 acc[4];
#pragma unroll
    for (int fm = 0; fm < 4; ++fm) acc[fm] = (f32x4)(0.0f);

    const int swz = (l15 & 7) * 8;         // read-side XOR

#pragma unroll
    for (int it = 0; it < 8; ++it) {
        const int k0 = it * 64;
        // stage A: wave w covers rows w*32..w*32+31 (4 gload16); B: rows w*8..w*8+7 (1)
#pragma unroll
        for (int j = 0; j < 4; ++j) {
            const int r0 = wave * 32 + j * 8;
            gload16(&zrow[(size_t)(r0 + l8) * D_DIM + k0 + cx], &As[r0 * 64]);
        }
        {
            const int r0 = wave * 8;
            gload16(&ant[(size_t)(mB + r0 + l8) * D_DIM + k0 + cx], &Bs[r0 * 64]);
        }
        __syncthreads();                   // drains vmcnt -> LDS visible

#pragma unroll
        for (int ks = 0; ks < 2; ++ks) {
            const int co = (ks * 32 + lhi * 8) ^ swz;
            const bf16x8 bfrag = *reinterpret_cast<const bf16x8*>(&Bs[(wc * 16 + l15) * 64 + co]);
#pragma unroll
            for (int fm = 0; fm < 4; ++fm) {
                const bf16x8 afrag = *reinterpret_cast<const bf16x8*>(&As[(wr * 64 + fm * 16 + l15) * 64 + co]);
                acc[fm] = __builtin_amdgcn_mfma_f32_16x16x32_bf16(afrag, bfrag, acc[fm], 0, 0, 0);
            }
        }
        __syncthreads();                   // readers done before next overwrite
    }

    // ---- CF: per lane m = mB + wc*16 + l15 fixed; 16 b-values in acc (R4 validated) ----
    f32x2 cs0  = {0.f, 0.f}, cs1  = {0.f, 0.f}, cs2  = {0.f, 0.f}, cs3  = {0.f, 0.f};
    f32x2 cs4  = {0.f, 0.f}, cs5  = {0.f, 0.f}, cs6  = {0.f, 0.f}, cs7  = {0.f, 0.f};
    f32x2 cs8  = {0.f, 0.f}, cs9  = {0.f, 0.f}, cs10 = {0.f, 0.f}, cs11 = {0.f, 0.f};
    f32x2 cs12 = {0.f, 0.f}, cs13 = {0.f, 0.f}, cs14 = {0.f, 0.f}, cs15 = {0.f, 0.f};

#pragma unroll
    for (int fm = 0; fm < 4; ++fm) {
        const f32x4 av = acc[fm];
        CF_ALL(av.x) CF_ALL(av.y) CF_ALL(av.z) CF_ALL(av.w)
    }

    // reduce over the wave's 64 b-rows (4 lhi lane-groups)
    RED(cs0)  RED(cs1)  RED(cs2)  RED(cs3)  RED(cs4)  RED(cs5)  RED(cs6)  RED(cs7)
    RED(cs8)  RED(cs9)  RED(cs10) RED(cs11) RED(cs12) RED(cs13) RED(cs14) RED(cs15)

    if (wr == 0 && lane < 16) {
        ST(cs0, 0)   ST(cs1, 1)   ST(cs2, 2)   ST(cs3, 3)
        ST(cs4, 4)   ST(cs5, 5)   ST(cs6, 6)   ST(cs7, 7)
        ST(cs8, 8)   ST(cs9, 9)   ST(cs10, 10) ST(cs11, 11)
        ST(cs12, 12) ST(cs13, 13) ST(cs14, 14) ST(cs15, 15)
    }
    __syncthreads();

    if (wr == 1) {
        const float invB = 1.0f / 128.0f;
        float s = 0.0f;
        FIN(cs0, 1)   FIN(cs1, 2)   FIN(cs2, 3)   FIN(cs3, 4)
        FIN(cs4, 5)   FIN(cs5, 6)   FIN(cs6, 7)   FIN(cs7, 8)
        FIN(cs8, 9)   FIN(cs9, 10)  FIN(cs10, 11) FIN(cs11, 12)
        FIN(cs12, 13) FIN(cs13, 14) FIN(cs14, 15) FIN(cs15, 16)
        // butterfly over 64 lanes: each l15 column counted 4x (lhi copies)
#pragma unroll
        for (int m = 1; m < 64; m <<= 1) s += __shfl_xor(s, m);
        if (lane == 0) bred[wc] = s;
    }
    __syncthreads();
    // out = (1/(T*M)) * B * mean-stuff: combined scale = 0.25 * 128 / 32768 = 1/1024
    if (tid == 0)
        atomicAdd(out, (bred[0] + bred[1]) * (1.0f / 1024.0f));
}

extern "C" void kernel_launch(void* const* d_in, const int* in_sizes, int n_in,
                              void* d_out, int out_size, void* d_ws, size_t ws_size,
                              hipStream_t stream) {
    const float* z = (const float*)d_in[0];   // (32,128,512)
    const float* A = (const float*)d_in[1];   // (512,1024)
    float* out = (float*)d_out;

    char* ws = (char*)d_ws;
    ushort* zb  = (ushort*)ws;                        // 4 MB
    ushort* ant = (ushort*)(ws + 4 * 1024 * 1024);    // 1 MB

    prep_kernel<<<320, 256, 0, stream>>>(A, z, zb, ant, out);
    fused_kernel<<<dim3(M_DIM / 32, T_DIM), 256, 0, stream>>>(zb, ant, out);
}